// Round 10
// baseline (921.094 us; speedup 1.0000x reference)
//
#include <hip/hip_runtime.h>

#define PN 50000
#define PE 1600000
#define PB 4096
#define NP 8          // dest partitions (XCD-pinned)
#define PSZ 6250      // partition size
#define NSW 4         // source windows
#define SWSZ 12500    // source window size
#define SCAP 210000   // staging capacity per partition (E/8 = 200K, +24 sigma)
#define SP 10         // dest-subparts per partition (hist/scatter blocks)
#define SPSZ 625      // dest nodes per subpart
#define GBLK 2048     // persistent gather blocks
#define NPER 7        // nodes per wave: ceil(50000 / (2048*4))

typedef __attribute__((ext_vector_type(8))) short bf16x8;
typedef __attribute__((ext_vector_type(4))) float f32x4;

__device__ inline float b2f(ushort u) {
    union { unsigned int i; float f; } x; x.i = ((unsigned int)u) << 16; return x.f;
}
__device__ inline ushort f2b(float f) {
    union { float f; unsigned int i; } x; x.f = f;
    unsigned int r = (x.i + 0x7FFFu + ((x.i >> 16) & 1u)) >> 16;
    return (ushort)r;
}

// ---------------- workspace layout (in 4-byte words) ----------------
static constexpr size_t L4N = 4 * (size_t)PN;                    // 200000 (node,window) keys
static constexpr size_t IDXCAP3 = PE + 3 * L4N + 1024;           // ushorts (4-padded segments)
static constexpr size_t OFF_BN     = 0;                          // 256 f
static constexpr size_t OFF_GCUR   = 256;                        // 16 int
static constexpr size_t OFF_TMPM   = 272;
static constexpr size_t OFF_M      = OFF_TMPM + 192 * 128;
static constexpr size_t OFF_WOFFU  = OFF_M + 192 * 192;          // 4N+4 int
static constexpr size_t OFF_WOFFD  = OFF_WOFFU + L4N + 4;
static constexpr size_t OFF_WDEGU  = OFF_WOFFD + L4N + 4;        // 4N int (true counts)
static constexpr size_t OFF_WDEGD  = OFF_WDEGU + L4N;
static constexpr size_t OFF_IDXU   = OFF_WDEGD + L4N;            // IDXCAP3 ushort
static constexpr size_t OFF_IDXD   = OFF_IDXU + (IDXCAP3 + 1) / 2;
static constexpr size_t OFF_STGU   = OFF_IDXD + (IDXCAP3 + 1) / 2;   // NP*SCAP u32
static constexpr size_t OFF_STGD   = OFF_STGU + NP * (size_t)SCAP;
static constexpr size_t OFF_WB16   = OFF_STGD + NP * (size_t)SCAP;   // 43008 words
static constexpr size_t OFF_HB     = OFF_WB16 + 43008;           // N*192 bf16
static constexpr size_t OFF_PROJ   = OFF_HB + (size_t)PN * 96;   // N*192 bf16

// ---------------- batchnorm stats ----------------
__global__ __launch_bounds__(256) void bn_stats_kernel(const float* __restrict__ x,
                                                       float* __restrict__ sums, int N) {
    __shared__ float ls[256], ls2[256];
    int col = threadIdx.x & 63;
    int rstart = blockIdx.x * 4 + (threadIdx.x >> 6);
    float s = 0.f, s2 = 0.f;
    for (int r = rstart; r < N; r += gridDim.x * 4) {
        float v = x[(size_t)r * 64 + col];
        s += v; s2 += v * v;
    }
    ls[threadIdx.x] = s; ls2[threadIdx.x] = s2;
    __syncthreads();
    if (threadIdx.x < 64) {
        s  = ls[threadIdx.x]  + ls[threadIdx.x + 64]  + ls[threadIdx.x + 128]  + ls[threadIdx.x + 192];
        s2 = ls2[threadIdx.x] + ls2[threadIdx.x + 64] + ls2[threadIdx.x + 128] + ls2[threadIdx.x + 192];
        atomicAdd(&sums[col], s);
        atomicAdd(&sums[64 + col], s2);
    }
}

__global__ __launch_bounds__(64) void bn_finalize_kernel(const float* __restrict__ gamma,
                                                         const float* __restrict__ beta,
                                                         float* __restrict__ bn, int N) {
    int c = threadIdx.x;
    float mean = bn[c] / (float)N;
    float var = bn[64 + c] / (float)N - mean * mean;
    float sc = gamma[c] * rsqrtf(var + 1e-5f);
    bn[128 + c] = sc;
    bn[192 + c] = beta[c] - mean * sc;
}

// ---------------- CSR1: edge binning (LDS buckets -> dense staging) ----------------
__global__ __launch_bounds__(256) void bin_kernel(const int* __restrict__ ei,
                                                  int* __restrict__ gcur,
                                                  uint* __restrict__ stgu,
                                                  uint* __restrict__ stgd, int E) {
    __shared__ uint sbuf[16][1024];     // 64 KB
    __shared__ int scnt[16], sbase[16];
    const int tid = threadIdx.x;
    for (int base = blockIdx.x * 1024; base < E; base += gridDim.x * 1024) {
        if (tid < 16) scnt[tid] = 0;
        __syncthreads();
#pragma unroll
        for (int j = 0; j < 4; ++j) {
            int e = base + j * 256 + tid;
            if (e < E) {
                int r = __builtin_nontemporal_load(&ei[e]);
                int c = __builtin_nontemporal_load(&ei[E + e]);
                int pu = c / PSZ;
                int slot = atomicAdd(&scnt[pu], 1);
                sbuf[pu][slot] = ((uint)c << 16) | (uint)r;
                int pd = r / PSZ;
                int slot2 = atomicAdd(&scnt[8 + pd], 1);
                sbuf[8 + pd][slot2] = ((uint)r << 16) | (uint)c;
            }
        }
        __syncthreads();
        if (tid < 16) sbase[tid] = atomicAdd(&gcur[tid], scnt[tid]);
        __syncthreads();
#pragma unroll 1
        for (int k = 0; k < 16; ++k) {
            int cnt = scnt[k];
            int gb = sbase[k];
            uint* dst = (k < 8) ? (stgu + (size_t)k * SCAP) : (stgd + (size_t)(k - 8) * SCAP);
            for (int i = tid; i < cnt; i += 256) {
                int gi = gb + i;
                if (gi < SCAP) dst[gi] = sbuf[k][i];
            }
        }
        __syncthreads();
    }
}

// ---------------- CSR2: hist over (dest,window), transposed decomposition ----------------
// grid NP*2*SP = 160: p = blk&7 (XCD-pinned), dir = (blk>>3)&1, sp = blk>>4.
// Block owns dest subrange [lo, lo+SPSZ), scans ALL of partition p's staging. LDS 10 KB.
__global__ __launch_bounds__(256) void hist_kernel(const uint* __restrict__ stgu,
                                                   const uint* __restrict__ stgd,
                                                   const int* __restrict__ gcur,
                                                   int* __restrict__ wdegu,
                                                   int* __restrict__ wdegd) {
    __shared__ int hist[SPSZ * NSW];    // 10 KB
    const int p = blockIdx.x & 7;
    const int dir = (blockIdx.x >> 3) & 1;
    const int sp = blockIdx.x >> 4;
    const int tid = threadIdx.x;
    const int lo = p * PSZ + sp * SPSZ;
    for (int i = tid; i < SPSZ * NSW; i += 256) hist[i] = 0;
    __syncthreads();
    const int cnt = min(gcur[dir * 8 + p], SCAP);
    const uint* stg = (dir ? stgd : stgu) + (size_t)p * SCAP;
    for (int i = tid; i < cnt; i += 256) {
        uint u = stg[i];
        int ld = (int)(u >> 16) - lo;
        if ((unsigned)ld < SPSZ)
            atomicAdd(&hist[ld * NSW + (int)(u & 0xFFFFu) / SWSZ], 1);
    }
    __syncthreads();
    int* wd = (dir ? wdegd : wdegu) + (size_t)lo * NSW;
    for (int i = tid; i < SPSZ * NSW; i += 256) wd[i] = hist[i];
}

// ---------------- scan: pad wdeg to 4; exclusive scan over 4N keys ----------------
__global__ __launch_bounds__(1024) void scan_kernel(const int* __restrict__ degA,
                                                    const int* __restrict__ degB,
                                                    int* __restrict__ offA,
                                                    int* __restrict__ offB, int len) {
    const int* deg = blockIdx.x ? degB : degA;
    int* off = blockIdx.x ? offB : offA;
    __shared__ int wsum[17];
    int tid = threadIdx.x, lane = tid & 63, wid = tid >> 6;
    int run = 0;
    for (int base = 0; base < len; base += 4096) {
        int i4 = base + tid * 4;
        int4 v = make_int4(0, 0, 0, 0);
        if (i4 < len) v = *(const int4*)&deg[i4];
        v.x = (v.x + 3) & ~3; v.y = (v.y + 3) & ~3;
        v.z = (v.z + 3) & ~3; v.w = (v.w + 3) & ~3;
        int lsum = v.x + v.y + v.z + v.w;
        int inc = lsum;
#pragma unroll
        for (int d = 1; d < 64; d <<= 1) {
            int t = __shfl_up(inc, d);
            if (lane >= d) inc += t;
        }
        if (lane == 63) wsum[wid] = inc;
        __syncthreads();
        if (tid == 0) {
            int r2 = 0;
#pragma unroll
            for (int i = 0; i < 16; ++i) { int t = wsum[i]; wsum[i] = r2; r2 += t; }
            wsum[16] = r2;
        }
        __syncthreads();
        if (i4 < len) {
            int pre = run + wsum[wid] + inc - lsum;
            int4 o;
            o.x = pre; o.y = pre + v.x; o.z = o.y + v.y; o.w = o.z + v.z;
            *(int4*)&off[i4] = o;
        }
        run += wsum[16];
        __syncthreads();
    }
    if (tid == 0) off[len] = run;
}

// ---------------- CSR3: scatter, transposed decomposition, LDS cursors (10 KB) ----------
__global__ __launch_bounds__(256) void scatter_kernel(const uint* __restrict__ stgu,
                                                      const uint* __restrict__ stgd,
                                                      const int* __restrict__ gcur,
                                                      const int* __restrict__ woffu,
                                                      const int* __restrict__ woffd,
                                                      ushort* __restrict__ idxu,
                                                      ushort* __restrict__ idxd) {
    __shared__ int cur[SPSZ * NSW];     // 10 KB
    const int p = blockIdx.x & 7;
    const int dir = (blockIdx.x >> 3) & 1;
    const int sp = blockIdx.x >> 4;
    const int tid = threadIdx.x;
    const int lo = p * PSZ + sp * SPSZ;
    const int* woff = (dir ? woffd : woffu) + (size_t)lo * NSW;
    for (int i = tid; i < SPSZ * NSW; i += 256) cur[i] = woff[i];
    __syncthreads();
    const int cnt = min(gcur[dir * 8 + p], SCAP);
    const uint* stg = (dir ? stgd : stgu) + (size_t)p * SCAP;
    ushort* idx = (dir ? idxd : idxu);
    for (int i = tid; i < cnt; i += 256) {
        uint u = stg[i];
        int ld = (int)(u >> 16) - lo;
        if ((unsigned)ld < SPSZ) {
            int src = (int)(u & 0xFFFFu);
            int pos = atomicAdd(&cur[ld * NSW + src / SWSZ], 1);
            idx[pos] = (ushort)src;
        }
    }
}

// ---------------- weight convert ----------------
template<int K>
__global__ __launch_bounds__(256) void wconv_kernel(const float* __restrict__ Wu,
                                                    const float* __restrict__ Wd,
                                                    const float* __restrict__ Wb,
                                                    ushort* __restrict__ out) {
    int idx = blockIdx.x * 256 + threadIdx.x;
    if (idx >= 192 * K) return;
    int c = idx / K, k = idx - c * K;
    const float* W = (c < 64) ? Wu : (c < 128 ? Wd : Wb);
    out[idx] = f2b(W[k * 64 + (c & 63)]);
}

// ---------------- MFMA GEMM: proj[N,192] = A[N,K] @ W[K,192] ----------------
template<int K, bool BN>
__global__ __launch_bounds__(256) void gemm_kernel(const ushort* __restrict__ hb,
                                                   const float* __restrict__ x,
                                                   const float* __restrict__ bn,
                                                   const ushort* __restrict__ wb,
                                                   ushort* __restrict__ proj, int nrows) {
    constexpr int KP = K + 8;
    __shared__ ushort wlds[192 * KP];
    const int tid = threadIdx.x;
    constexpr int KB8 = K / 8;
    for (int idx = tid; idx < 192 * KB8; idx += 256) {
        int col = idx / KB8, kb = idx - col * KB8;
        *(bf16x8*)&wlds[col * KP + kb * 8] = *(const bf16x8*)&wb[(size_t)col * K + kb * 8];
    }
    __syncthreads();
    const int lane = tid & 63, wid = tid >> 6;
    const int kgrp = (lane >> 4) * 8;
    const int rbase = blockIdx.x * 128 + wid * 32;
    int ar[2] = { min(rbase + (lane & 15), nrows - 1),
                  min(rbase + 16 + (lane & 15), nrows - 1) };
    f32x4 acc[2][12];
#pragma unroll
    for (int rt = 0; rt < 2; ++rt)
#pragma unroll
        for (int ct = 0; ct < 12; ++ct) acc[rt][ct] = (f32x4)0.0f;

#pragma unroll
    for (int k0 = 0; k0 < K; k0 += 32) {
        bf16x8 af[2];
        if (BN) {
#pragma unroll
            for (int rt = 0; rt < 2; ++rt)
#pragma unroll
                for (int j = 0; j < 8; ++j) {
                    int c = k0 + kgrp + j;
                    float v = x[(size_t)ar[rt] * 64 + c] * bn[128 + c] + bn[192 + c];
                    af[rt][j] = (short)f2b(v);
                }
        } else {
#pragma unroll
            for (int rt = 0; rt < 2; ++rt)
                af[rt] = *(const bf16x8*)&hb[(size_t)ar[rt] * 192 + k0 + kgrp];
        }
#pragma unroll
        for (int ct = 0; ct < 12; ++ct) {
            bf16x8 bfr = *(const bf16x8*)&wlds[(ct * 16 + (lane & 15)) * KP + k0 + kgrp];
            acc[0][ct] = __builtin_amdgcn_mfma_f32_16x16x32_bf16(af[0], bfr, acc[0][ct], 0, 0, 0);
            acc[1][ct] = __builtin_amdgcn_mfma_f32_16x16x32_bf16(af[1], bfr, acc[1][ct], 0, 0, 0);
        }
    }
    const int orow0 = blockIdx.x * 128 + wid * 32 + (lane >> 4) * 4;
#pragma unroll
    for (int rt = 0; rt < 2; ++rt)
#pragma unroll
        for (int ct = 0; ct < 12; ++ct) {
            int ocol = ct * 16 + (lane & 15);
#pragma unroll
            for (int j = 0; j < 4; ++j) {
                int orow = orow0 + rt * 16 + j;
                if (orow < nrows) proj[(size_t)orow * 192 + ocol] = f2b(acc[rt][ct][j]);
            }
        }
}

// ---------------- persistent windowed gather + normalize + leaky ----------------
__global__ __launch_bounds__(256) void gather_kernel(const ushort* __restrict__ proj,
                                                     const int* __restrict__ woffu,
                                                     const int* __restrict__ wdegu,
                                                     const int* __restrict__ woffd,
                                                     const int* __restrict__ wdegd,
                                                     const ushort* __restrict__ idxu,
                                                     const ushort* __restrict__ idxd,
                                                     ushort* __restrict__ hb, int N) {
    const int gw = blockIdx.x * 4 + (threadIdx.x >> 6);
    const int nwaves = gridDim.x * 4;
    const int lane = threadIdx.x & 63;
    const int half = lane >> 5;          // 0 = up, 1 = dn
    const int sl = lane & 31;
    const int* __restrict__ woff = half ? woffd : woffu;
    const int* __restrict__ wdeg = half ? wdegd : wdegu;
    const ushort* __restrict__ idx = half ? idxd : idxu;
    const uint* __restrict__ rowb = (const uint*)proj + half * 32 + sl;

    float a0[NPER], a1[NPER];
    int dtot[NPER];
#pragma unroll
    for (int j = 0; j < NPER; ++j) { a0[j] = 0.f; a1[j] = 0.f; dtot[j] = 0; }

    for (int w = 0; w < NSW; ++w) {
#pragma unroll
        for (int j = 0; j < NPER; ++j) {
            int n = gw + j * nwaves;
            if (n < N) {
                int key = n * NSW + w;
                int s = woff[key];
                int cnt = wdeg[key];
                dtot[j] += cnt;
                const ushort* p = idx + s;
                for (int i = 0; i < cnt; i += 4) {
                    ushort4 U = *(const ushort4*)(p + i);   // 4-padded: in-bounds
                    int v1 = (i + 1 < cnt), v2 = (i + 2 < cnt), v3 = (i + 3 < cnt);
                    int s0 = (int)U.x;
                    int s1 = v1 ? (int)U.y : 0;
                    int s2 = v2 ? (int)U.z : 0;
                    int s3 = v3 ? (int)U.w : 0;
                    uint w0 = rowb[(size_t)s0 * 96];
                    uint w1 = rowb[(size_t)s1 * 96];
                    uint w2 = rowb[(size_t)s2 * 96];
                    uint w3 = rowb[(size_t)s3 * 96];
                    if (!v1) w1 = 0; if (!v2) w2 = 0; if (!v3) w3 = 0;
                    a0[j] += __uint_as_float(w0 << 16) + __uint_as_float(w1 << 16)
                           + __uint_as_float(w2 << 16) + __uint_as_float(w3 << 16);
                    a1[j] += __uint_as_float(w0 & 0xFFFF0000u) + __uint_as_float(w1 & 0xFFFF0000u)
                           + __uint_as_float(w2 & 0xFFFF0000u) + __uint_as_float(w3 & 0xFFFF0000u);
                }
            }
        }
        __syncthreads();   // keep the block's 4 waves in phase
    }

    uint* hb32 = (uint*)hb;
#pragma unroll
    for (int j = 0; j < NPER; ++j) {
        int n = gw + j * nwaves;
        if (n >= N) continue;
        float sc = 1.0f / (float)max(dtot[j], 1);
        float A0 = a0[j] * sc, A1 = a1[j] * sc;
        uint bw = (half == 0) ? ((const uint*)proj)[(size_t)n * 96 + 64 + sl] : 0u;
        float b0 = __uint_as_float(bw << 16);
        float b1 = __uint_as_float(bw & 0xFFFF0000u);
        float ss = A0 * A0 + A1 * A1 + b0 * b0 + b1 * b1;
#pragma unroll
        for (int off = 32; off; off >>= 1) ss += __shfl_xor(ss, off);
        float r = 1.0f / fmaxf(sqrtf(ss), 1e-12f);
        A0 *= r; A1 *= r; b0 *= r; b1 *= r;
        A0 = A0 >= 0.f ? A0 : 0.1f * A0;
        A1 = A1 >= 0.f ? A1 : 0.1f * A1;
        hb32[(size_t)n * 96 + half * 32 + sl] = (uint)f2b(A0) | ((uint)f2b(A1) << 16);
        if (half == 0) {
            b0 = b0 >= 0.f ? b0 : 0.1f * b0;
            b1 = b1 >= 0.f ? b1 : 0.1f * b1;
            hb32[(size_t)n * 96 + 64 + sl] = (uint)f2b(b0) | ((uint)f2b(b1) << 16);
        }
    }
}

// ---------------- decoder ----------------
__global__ __launch_bounds__(128) void m1_kernel(const float* __restrict__ P1,
                                                 const float* __restrict__ P2,
                                                 float* __restrict__ tmpM) {
    int i = blockIdx.x, c = threadIdx.x;
    float s = 0.f;
    for (int k = 0; k < 128; ++k) s += P1[i * 128 + k] * P2[k * 128 + c];
    tmpM[i * 128 + c] = s;
}

__global__ __launch_bounds__(192) void m2_kernel(const float* __restrict__ tmpM,
                                                 const float* __restrict__ P1,
                                                 float* __restrict__ M) {
    __shared__ float trow[128];
    int i = blockIdx.x, j = threadIdx.x;
    if (j < 128) trow[j] = tmpM[i * 128 + j];
    __syncthreads();
    float s = 0.f;
    for (int k = 0; k < 128; ++k) s += trow[k] * P1[j * 128 + k];
    M[i * 192 + j] = s;
}

__global__ __launch_bounds__(192) void decode_kernel(const ushort* __restrict__ hb,
                                                     const int* __restrict__ di,
                                                     const float* __restrict__ M,
                                                     float* __restrict__ out) {
    __shared__ alignas(16) float bvs[8][192];
    __shared__ float red[3][8];
    int pb = blockIdx.x * 8;
    int i = threadIdx.x;
#pragma unroll
    for (int p = 0; p < 8; ++p) {
        int nb = di[(pb + p) * 2 + 1] - 1;
        bvs[p][i] = b2f(hb[(size_t)nb * 192 + i]);
    }
    __syncthreads();
    float t[8] = {};
    const float4* M4 = (const float4*)(M + (size_t)i * 192);
    for (int j4 = 0; j4 < 48; ++j4) {
        float4 m = M4[j4];
#pragma unroll
        for (int p = 0; p < 8; ++p) {
            float4 b = *(const float4*)&bvs[p][j4 * 4];
            t[p] += m.x * b.x + m.y * b.y + m.z * b.z + m.w * b.w;
        }
    }
    int wid = i >> 6, lane = i & 63;
#pragma unroll
    for (int p = 0; p < 8; ++p) {
        int na = di[(pb + p) * 2] - 1;
        float v = b2f(hb[(size_t)na * 192 + i]) * t[p];
#pragma unroll
        for (int off = 32; off; off >>= 1) v += __shfl_xor(v, off);
        if (lane == 0) red[wid][p] = v;
    }
    __syncthreads();
    if (i < 8) out[pb + i] = red[0][i] + red[1][i] + red[2][i];
}

extern "C" void kernel_launch(void* const* d_in, const int* in_sizes, int n_in,
                              void* d_out, int out_size, void* d_ws, size_t ws_size,
                              hipStream_t stream) {
    const float* x     = (const float*)d_in[0];
    const int*   ei    = (const int*)d_in[1];
    const int*   di    = (const int*)d_in[2];
    const float* gamma = (const float*)d_in[3];
    const float* beta  = (const float*)d_in[4];
    const float* Wu[3] = {(const float*)d_in[5], (const float*)d_in[8],  (const float*)d_in[11]};
    const float* Wd[3] = {(const float*)d_in[6], (const float*)d_in[9],  (const float*)d_in[12]};
    const float* Wb[3] = {(const float*)d_in[7], (const float*)d_in[10], (const float*)d_in[13]};
    const float* P1    = (const float*)d_in[14];
    const float* P2    = (const float*)d_in[15];
    float* out = (float*)d_out;
    float* ws  = (float*)d_ws;

    float* bn    = ws + OFF_BN;
    int* gcur  = (int*)(ws + OFF_GCUR);
    float* tmpM  = ws + OFF_TMPM;
    float* M     = ws + OFF_M;
    int* woffu = (int*)(ws + OFF_WOFFU);
    int* woffd = (int*)(ws + OFF_WOFFD);
    int* wdegu = (int*)(ws + OFF_WDEGU);
    int* wdegd = (int*)(ws + OFF_WDEGD);
    ushort* idxu = (ushort*)(ws + OFF_IDXU);
    ushort* idxd = (ushort*)(ws + OFF_IDXD);
    uint* stgu = (uint*)(ws + OFF_STGU);
    uint* stgd = (uint*)(ws + OFF_STGD);
    ushort* wb16 = (ushort*)(ws + OFF_WB16);
    ushort* hb   = (ushort*)(ws + OFF_HB);
    ushort* proj = (ushort*)(ws + OFF_PROJ);
    ushort* wbl[3] = {wb16, wb16 + 12288, wb16 + 49152};

    hipMemsetAsync(ws, 0, 272 * sizeof(float), stream);   // bn sums + gcur

    bn_stats_kernel<<<200, 256, 0, stream>>>(x, bn, PN);
    bn_finalize_kernel<<<1, 64, 0, stream>>>(gamma, beta, bn, PN);

    bin_kernel<<<512, 256, 0, stream>>>(ei, gcur, stgu, stgd, PE);
    hist_kernel<<<NP * 2 * SP, 256, 0, stream>>>(stgu, stgd, gcur, wdegu, wdegd);
    scan_kernel<<<2, 1024, 0, stream>>>(wdegu, wdegd, woffu, woffd, (int)L4N);
    scatter_kernel<<<NP * 2 * SP, 256, 0, stream>>>(stgu, stgd, gcur, woffu, woffd, idxu, idxd);

    wconv_kernel<64><<<(192 * 64 + 255) / 256, 256, 0, stream>>>(Wu[0], Wd[0], Wb[0], wbl[0]);
    wconv_kernel<192><<<(192 * 192 + 255) / 256, 256, 0, stream>>>(Wu[1], Wd[1], Wb[1], wbl[1]);
    wconv_kernel<192><<<(192 * 192 + 255) / 256, 256, 0, stream>>>(Wu[2], Wd[2], Wb[2], wbl[2]);

    const int ngb = (PN + 127) / 128;
    gemm_kernel<64, true><<<ngb, 256, 0, stream>>>(hb, x, bn, wbl[0], proj, PN);
    gather_kernel<<<GBLK, 256, 0, stream>>>(proj, woffu, wdegu, woffd, wdegd, idxu, idxd, hb, PN);
    gemm_kernel<192, false><<<ngb, 256, 0, stream>>>(hb, x, bn, wbl[1], proj, PN);
    gather_kernel<<<GBLK, 256, 0, stream>>>(proj, woffu, wdegu, woffd, wdegd, idxu, idxd, hb, PN);
    gemm_kernel<192, false><<<ngb, 256, 0, stream>>>(hb, x, bn, wbl[2], proj, PN);
    gather_kernel<<<GBLK, 256, 0, stream>>>(proj, woffu, wdegu, woffd, wdegd, idxu, idxd, hb, PN);

    m1_kernel<<<192, 128, 0, stream>>>(P1, P2, tmpM);
    m2_kernel<<<192, 192, 0, stream>>>(tmpM, P1, M);
    decode_kernel<<<PB / 8, 192, 0, stream>>>(hb, di, M, out);
}

// Round 11
// 699.497 us; speedup vs baseline: 1.3168x; 1.3168x over previous
//
#include <hip/hip_runtime.h>

#define PN 50000
#define PE 1600000
#define PB 4096
#define NP 8          // dest partitions (XCD-pinned)
#define PSZ 6250      // partition size
#define NSW 4         // source windows
#define SWSZ 12500    // source window size
#define SCAP 210000   // staging capacity per (partition,dir)
#define CCAP 60000    // chunk capacity per (partition,dir,window)
#define NSL2 4        // slices per chunk for hist/scatter
#define GBLK 2048     // persistent gather blocks
#define NPER 7        // nodes per wave: ceil(50000 / (2048*4))

typedef __attribute__((ext_vector_type(8))) short bf16x8;
typedef __attribute__((ext_vector_type(4))) float f32x4;

__device__ inline float b2f(ushort u) {
    union { unsigned int i; float f; } x; x.i = ((unsigned int)u) << 16; return x.f;
}
__device__ inline ushort f2b(float f) {
    union { float f; unsigned int i; } x; x.f = f;
    unsigned int r = (x.i + 0x7FFFu + ((x.i >> 16) & 1u)) >> 16;
    return (ushort)r;
}

// ---------------- workspace layout (in 4-byte words) ----------------
static constexpr size_t L4N = 4 * (size_t)PN;                    // 200000 (node,window) keys
static constexpr size_t IDXCAP3 = PE + 3 * L4N + 1024;           // ushorts (4-padded segments)
static constexpr size_t OFF_BN     = 0;                          // 256 f
static constexpr size_t OFF_GCUR   = 256;                        // 16 int
static constexpr size_t OFF_CCUR   = 272;                        // 64 int
static constexpr size_t OFF_TMPM   = 336;
static constexpr size_t OFF_M      = OFF_TMPM + 192 * 128;
static constexpr size_t OFF_WOFFU  = OFF_M + 192 * 192;          // 4N+4 int
static constexpr size_t OFF_WOFFD  = OFF_WOFFU + L4N + 4;
static constexpr size_t OFF_WDEGU  = OFF_WOFFD + L4N + 4;        // 4N int (true counts)
static constexpr size_t OFF_WDEGD  = OFF_WDEGU + L4N;
static constexpr size_t OFF_PHISTU = OFF_WDEGD + L4N;            // NSL2*4N int
static constexpr size_t OFF_PHISTD = OFF_PHISTU + NSL2 * L4N;
static constexpr size_t OFF_IDXU   = OFF_PHISTD + NSL2 * L4N;    // IDXCAP3 ushort
static constexpr size_t OFF_IDXD   = OFF_IDXU + (IDXCAP3 + 1) / 2;
static constexpr size_t OFF_STGU   = OFF_IDXD + (IDXCAP3 + 1) / 2;   // NP*SCAP u32
static constexpr size_t OFF_STGD   = OFF_STGU + NP * (size_t)SCAP;
static constexpr size_t OFF_CHK    = OFF_STGD + NP * (size_t)SCAP;   // 64*CCAP u32
static constexpr size_t OFF_WB16   = OFF_CHK + 64 * (size_t)CCAP;    // 43008 words
static constexpr size_t OFF_HB     = OFF_WB16 + 43008;           // N*192 bf16
static constexpr size_t OFF_PROJ   = OFF_HB + (size_t)PN * 96;   // N*192 bf16

// ---------------- batchnorm stats ----------------
__global__ __launch_bounds__(256) void bn_stats_kernel(const float* __restrict__ x,
                                                       float* __restrict__ sums, int N) {
    __shared__ float ls[256], ls2[256];
    int col = threadIdx.x & 63;
    int rstart = blockIdx.x * 4 + (threadIdx.x >> 6);
    float s = 0.f, s2 = 0.f;
    for (int r = rstart; r < N; r += gridDim.x * 4) {
        float v = x[(size_t)r * 64 + col];
        s += v; s2 += v * v;
    }
    ls[threadIdx.x] = s; ls2[threadIdx.x] = s2;
    __syncthreads();
    if (threadIdx.x < 64) {
        s  = ls[threadIdx.x]  + ls[threadIdx.x + 64]  + ls[threadIdx.x + 128]  + ls[threadIdx.x + 192];
        s2 = ls2[threadIdx.x] + ls2[threadIdx.x + 64] + ls2[threadIdx.x + 128] + ls2[threadIdx.x + 192];
        atomicAdd(&sums[col], s);
        atomicAdd(&sums[64 + col], s2);
    }
}

__global__ __launch_bounds__(64) void bn_finalize_kernel(const float* __restrict__ gamma,
                                                         const float* __restrict__ beta,
                                                         float* __restrict__ bn, int N) {
    int c = threadIdx.x;
    float mean = bn[c] / (float)N;
    float var = bn[64 + c] / (float)N - mean * mean;
    float sc = gamma[c] * rsqrtf(var + 1e-5f);
    bn[128 + c] = sc;
    bn[192 + c] = beta[c] - mean * sc;
}

// ---------------- CSR1: edge binning (LDS buckets -> dense dest-partition staging) -------
__global__ __launch_bounds__(256) void bin_kernel(const int* __restrict__ ei,
                                                  int* __restrict__ gcur,
                                                  uint* __restrict__ stgu,
                                                  uint* __restrict__ stgd, int E) {
    __shared__ uint sbuf[16][1024];     // 64 KB
    __shared__ int scnt[16], sbase[16];
    const int tid = threadIdx.x;
    for (int base = blockIdx.x * 1024; base < E; base += gridDim.x * 1024) {
        if (tid < 16) scnt[tid] = 0;
        __syncthreads();
#pragma unroll
        for (int j = 0; j < 4; ++j) {
            int e = base + j * 256 + tid;
            if (e < E) {
                int r = __builtin_nontemporal_load(&ei[e]);
                int c = __builtin_nontemporal_load(&ei[E + e]);
                int pu = c / PSZ;
                int slot = atomicAdd(&scnt[pu], 1);
                sbuf[pu][slot] = ((uint)c << 16) | (uint)r;
                int pd = r / PSZ;
                int slot2 = atomicAdd(&scnt[8 + pd], 1);
                sbuf[8 + pd][slot2] = ((uint)r << 16) | (uint)c;
            }
        }
        __syncthreads();
        if (tid < 16) sbase[tid] = atomicAdd(&gcur[tid], scnt[tid]);
        __syncthreads();
#pragma unroll 1
        for (int k = 0; k < 16; ++k) {
            int cnt = scnt[k];
            int gb = sbase[k];
            uint* dst = (k < 8) ? (stgu + (size_t)k * SCAP) : (stgd + (size_t)(k - 8) * SCAP);
            for (int i = tid; i < cnt; i += 256) {
                int gi = gb + i;
                if (gi < SCAP) dst[gi] = sbuf[k][i];
            }
        }
        __syncthreads();
    }
}

// ---------------- CSR1b: rebin each (p,dir) staging by source window into chunks ----------
// grid 128: p = blk&7 (XCD-pinned), dir = (blk>>3)&1, slice = blk>>4 (8 slices)
__global__ __launch_bounds__(256) void rebin_kernel(const uint* __restrict__ stgu,
                                                    const uint* __restrict__ stgd,
                                                    const int* __restrict__ gcur,
                                                    int* __restrict__ ccur,
                                                    uint* __restrict__ chk) {
    __shared__ uint sb[4][1024];        // 16 KB
    __shared__ int sc[4], sbase[4];
    const int p = blockIdx.x & 7;
    const int dir = (blockIdx.x >> 3) & 1;
    const int sl = blockIdx.x >> 4;
    const int tid = threadIdx.x;
    const int cnt = min(gcur[dir * 8 + p], SCAP);
    const uint* stg = (dir ? stgd : stgu) + (size_t)p * SCAP;
    const int cbase = p + dir * 8;      // chunk id = cbase + 16*w
    const int per = (cnt + 7) / 8;
    const int s0 = sl * per, s1 = min(cnt, s0 + per);
    for (int base = s0; base < s1; base += 1024) {
        if (tid < 4) sc[tid] = 0;
        __syncthreads();
#pragma unroll
        for (int j = 0; j < 4; ++j) {
            int i = base + j * 256 + tid;
            if (i < s1) {
                uint u = stg[i];
                int w = (int)(u & 0xFFFFu) / SWSZ;
                int slot = atomicAdd(&sc[w], 1);
                sb[w][slot] = u;
            }
        }
        __syncthreads();
        if (tid < 4) sbase[tid] = atomicAdd(&ccur[cbase + 16 * tid], sc[tid]);
        __syncthreads();
#pragma unroll 1
        for (int k = 0; k < 4; ++k) {
            int ck = sc[k];
            int gb = sbase[k];
            uint* dst = chk + (size_t)(cbase + 16 * k) * CCAP;
            for (int i = tid; i < ck; i += 256) {
                int gi = gb + i;
                if (gi < CCAP) dst[gi] = sb[k][i];
            }
        }
        __syncthreads();
    }
}

// ---------------- CSR2: per-(chunk,slice) histogram, LDS 25 KB ----------------
// grid 64*NSL2: c = blk&63 (p = c&7 -> XCD-pinned), s = blk>>6
__global__ __launch_bounds__(256) void hist_kernel(const uint* __restrict__ chk,
                                                   const int* __restrict__ ccur,
                                                   int* __restrict__ phistu,
                                                   int* __restrict__ phistd) {
    __shared__ int hist[PSZ];           // 25 KB
    const int c = blockIdx.x & 63;
    const int s = blockIdx.x >> 6;
    const int p = c & 7;
    const int dir = (c >> 3) & 1;
    const int w = c >> 4;
    const int tid = threadIdx.x;
    const int lo = p * PSZ;
    for (int i = tid; i < PSZ; i += 256) hist[i] = 0;
    __syncthreads();
    const int cnt = min(ccur[c], CCAP);
    const uint* stg = chk + (size_t)c * CCAP;
    const int per = (cnt + NSL2 - 1) / NSL2;
    const int s0 = s * per, s1 = min(cnt, s0 + per);
    for (int i = s0 + tid; i < s1; i += 256)
        atomicAdd(&hist[(int)(stg[i] >> 16) - lo], 1);
    __syncthreads();
    int* ph = (dir ? phistd : phistu) + (size_t)s * L4N;
    for (int i = tid; i < PSZ; i += 256) ph[(size_t)(lo + i) * NSW + w] = hist[i];
}

// ---------------- scan: wdeg = sum slices; pad to 4; exclusive scan over 4N keys --------
__global__ __launch_bounds__(1024) void scan_kernel(const int* __restrict__ phA,
                                                    const int* __restrict__ phB,
                                                    int* __restrict__ offA,
                                                    int* __restrict__ offB,
                                                    int* __restrict__ degA,
                                                    int* __restrict__ degB, int len) {
    const int* ph = blockIdx.x ? phB : phA;
    int* off = blockIdx.x ? offB : offA;
    int* dego = blockIdx.x ? degB : degA;
    __shared__ int wsum[17];
    int tid = threadIdx.x, lane = tid & 63, wid = tid >> 6;
    int run = 0;
    for (int base = 0; base < len; base += 4096) {
        int i4 = base + tid * 4;
        int4 v = make_int4(0, 0, 0, 0);
        if (i4 < len) {
#pragma unroll
            for (int sl = 0; sl < NSL2; ++sl) {
                int4 t = *(const int4*)&ph[(size_t)sl * len + i4];
                v.x += t.x; v.y += t.y; v.z += t.z; v.w += t.w;
            }
            *(int4*)&dego[i4] = v;
        }
        v.x = (v.x + 3) & ~3; v.y = (v.y + 3) & ~3;
        v.z = (v.z + 3) & ~3; v.w = (v.w + 3) & ~3;
        int lsum = v.x + v.y + v.z + v.w;
        int inc = lsum;
#pragma unroll
        for (int d = 1; d < 64; d <<= 1) {
            int t = __shfl_up(inc, d);
            if (lane >= d) inc += t;
        }
        if (lane == 63) wsum[wid] = inc;
        __syncthreads();
        if (tid == 0) {
            int r2 = 0;
#pragma unroll
            for (int i = 0; i < 16; ++i) { int t = wsum[i]; wsum[i] = r2; r2 += t; }
            wsum[16] = r2;
        }
        __syncthreads();
        if (i4 < len) {
            int pre = run + wsum[wid] + inc - lsum;
            int4 o;
            o.x = pre; o.y = pre + v.x; o.z = o.y + v.y; o.w = o.z + v.z;
            *(int4*)&off[i4] = o;
        }
        run += wsum[16];
        __syncthreads();
    }
    if (tid == 0) off[len] = run;
}

// ---------------- CSR3: per-(chunk,slice) scatter with LDS cursors (25 KB) ----------------
__global__ __launch_bounds__(256) void scatter_kernel(const uint* __restrict__ chk,
                                                      const int* __restrict__ ccur,
                                                      const int* __restrict__ phistu,
                                                      const int* __restrict__ phistd,
                                                      const int* __restrict__ woffu,
                                                      const int* __restrict__ woffd,
                                                      ushort* __restrict__ idxu,
                                                      ushort* __restrict__ idxd) {
    __shared__ int cur[PSZ];            // 25 KB
    const int c = blockIdx.x & 63;
    const int s = blockIdx.x >> 6;
    const int p = c & 7;
    const int dir = (c >> 3) & 1;
    const int w = c >> 4;
    const int tid = threadIdx.x;
    const int lo = p * PSZ;
    const int* woff = (dir ? woffd : woffu);
    const int* phist = (dir ? phistd : phistu);
    for (int i = tid; i < PSZ; i += 256) {
        size_t key = (size_t)(lo + i) * NSW + w;
        int cv = woff[key];
        for (int t = 0; t < s; ++t) cv += phist[(size_t)t * L4N + key];
        cur[i] = cv;
    }
    __syncthreads();
    const int cnt = min(ccur[c], CCAP);
    const uint* stg = chk + (size_t)c * CCAP;
    ushort* idx = (dir ? idxd : idxu);
    const int per = (cnt + NSL2 - 1) / NSL2;
    const int s0 = s * per, s1 = min(cnt, s0 + per);
    for (int i = s0 + tid; i < s1; i += 256) {
        uint u = stg[i];
        int pos = atomicAdd(&cur[(int)(u >> 16) - lo], 1);
        idx[pos] = (ushort)(u & 0xFFFFu);
    }
}

// ---------------- weight convert ----------------
template<int K>
__global__ __launch_bounds__(256) void wconv_kernel(const float* __restrict__ Wu,
                                                    const float* __restrict__ Wd,
                                                    const float* __restrict__ Wb,
                                                    ushort* __restrict__ out) {
    int idx = blockIdx.x * 256 + threadIdx.x;
    if (idx >= 192 * K) return;
    int c = idx / K, k = idx - c * K;
    const float* W = (c < 64) ? Wu : (c < 128 ? Wd : Wb);
    out[idx] = f2b(W[k * 64 + (c & 63)]);
}

// ---------------- MFMA GEMM: proj[N,192] = A[N,K] @ W[K,192] ----------------
template<int K, bool BN>
__global__ __launch_bounds__(256) void gemm_kernel(const ushort* __restrict__ hb,
                                                   const float* __restrict__ x,
                                                   const float* __restrict__ bn,
                                                   const ushort* __restrict__ wb,
                                                   ushort* __restrict__ proj, int nrows) {
    constexpr int KP = K + 8;
    __shared__ ushort wlds[192 * KP];
    const int tid = threadIdx.x;
    constexpr int KB8 = K / 8;
    for (int idx = tid; idx < 192 * KB8; idx += 256) {
        int col = idx / KB8, kb = idx - col * KB8;
        *(bf16x8*)&wlds[col * KP + kb * 8] = *(const bf16x8*)&wb[(size_t)col * K + kb * 8];
    }
    __syncthreads();
    const int lane = tid & 63, wid = tid >> 6;
    const int kgrp = (lane >> 4) * 8;
    const int rbase = blockIdx.x * 128 + wid * 32;
    int ar[2] = { min(rbase + (lane & 15), nrows - 1),
                  min(rbase + 16 + (lane & 15), nrows - 1) };
    f32x4 acc[2][12];
#pragma unroll
    for (int rt = 0; rt < 2; ++rt)
#pragma unroll
        for (int ct = 0; ct < 12; ++ct) acc[rt][ct] = (f32x4)0.0f;

#pragma unroll
    for (int k0 = 0; k0 < K; k0 += 32) {
        bf16x8 af[2];
        if (BN) {
#pragma unroll
            for (int rt = 0; rt < 2; ++rt)
#pragma unroll
                for (int j = 0; j < 8; ++j) {
                    int c = k0 + kgrp + j;
                    float v = x[(size_t)ar[rt] * 64 + c] * bn[128 + c] + bn[192 + c];
                    af[rt][j] = (short)f2b(v);
                }
        } else {
#pragma unroll
            for (int rt = 0; rt < 2; ++rt)
                af[rt] = *(const bf16x8*)&hb[(size_t)ar[rt] * 192 + k0 + kgrp];
        }
#pragma unroll
        for (int ct = 0; ct < 12; ++ct) {
            bf16x8 bfr = *(const bf16x8*)&wlds[(ct * 16 + (lane & 15)) * KP + k0 + kgrp];
            acc[0][ct] = __builtin_amdgcn_mfma_f32_16x16x32_bf16(af[0], bfr, acc[0][ct], 0, 0, 0);
            acc[1][ct] = __builtin_amdgcn_mfma_f32_16x16x32_bf16(af[1], bfr, acc[1][ct], 0, 0, 0);
        }
    }
    const int orow0 = blockIdx.x * 128 + wid * 32 + (lane >> 4) * 4;
#pragma unroll
    for (int rt = 0; rt < 2; ++rt)
#pragma unroll
        for (int ct = 0; ct < 12; ++ct) {
            int ocol = ct * 16 + (lane & 15);
#pragma unroll
            for (int j = 0; j < 4; ++j) {
                int orow = orow0 + rt * 16 + j;
                if (orow < nrows) proj[(size_t)orow * 192 + ocol] = f2b(acc[rt][ct][j]);
            }
        }
}

// ---------------- persistent windowed gather + normalize + leaky ----------------
__global__ __launch_bounds__(256) void gather_kernel(const ushort* __restrict__ proj,
                                                     const int* __restrict__ woffu,
                                                     const int* __restrict__ wdegu,
                                                     const int* __restrict__ woffd,
                                                     const int* __restrict__ wdegd,
                                                     const ushort* __restrict__ idxu,
                                                     const ushort* __restrict__ idxd,
                                                     ushort* __restrict__ hb, int N) {
    const int gw = blockIdx.x * 4 + (threadIdx.x >> 6);
    const int nwaves = gridDim.x * 4;
    const int lane = threadIdx.x & 63;
    const int half = lane >> 5;          // 0 = up, 1 = dn
    const int sl = lane & 31;
    const int* __restrict__ woff = half ? woffd : woffu;
    const int* __restrict__ wdeg = half ? wdegd : wdegu;
    const ushort* __restrict__ idx = half ? idxd : idxu;
    const uint* __restrict__ rowb = (const uint*)proj + half * 32 + sl;

    float a0[NPER], a1[NPER];
    int dtot[NPER];
#pragma unroll
    for (int j = 0; j < NPER; ++j) { a0[j] = 0.f; a1[j] = 0.f; dtot[j] = 0; }

    for (int w = 0; w < NSW; ++w) {
#pragma unroll
        for (int j = 0; j < NPER; ++j) {
            int n = gw + j * nwaves;
            if (n < N) {
                int key = n * NSW + w;
                int s = woff[key];
                int cnt = wdeg[key];
                dtot[j] += cnt;
                const ushort* p = idx + s;
                for (int i = 0; i < cnt; i += 4) {
                    ushort4 U = *(const ushort4*)(p + i);   // 4-padded: in-bounds
                    int v1 = (i + 1 < cnt), v2 = (i + 2 < cnt), v3 = (i + 3 < cnt);
                    int s0 = (int)U.x;
                    int s1 = v1 ? (int)U.y : 0;
                    int s2 = v2 ? (int)U.z : 0;
                    int s3 = v3 ? (int)U.w : 0;
                    uint w0 = rowb[(size_t)s0 * 96];
                    uint w1 = rowb[(size_t)s1 * 96];
                    uint w2 = rowb[(size_t)s2 * 96];
                    uint w3 = rowb[(size_t)s3 * 96];
                    if (!v1) w1 = 0; if (!v2) w2 = 0; if (!v3) w3 = 0;
                    a0[j] += __uint_as_float(w0 << 16) + __uint_as_float(w1 << 16)
                           + __uint_as_float(w2 << 16) + __uint_as_float(w3 << 16);
                    a1[j] += __uint_as_float(w0 & 0xFFFF0000u) + __uint_as_float(w1 & 0xFFFF0000u)
                           + __uint_as_float(w2 & 0xFFFF0000u) + __uint_as_float(w3 & 0xFFFF0000u);
                }
            }
        }
        __syncthreads();   // keep the block's 4 waves in phase
    }

    uint* hb32 = (uint*)hb;
#pragma unroll
    for (int j = 0; j < NPER; ++j) {
        int n = gw + j * nwaves;
        if (n >= N) continue;
        float sc = 1.0f / (float)max(dtot[j], 1);
        float A0 = a0[j] * sc, A1 = a1[j] * sc;
        uint bw = (half == 0) ? ((const uint*)proj)[(size_t)n * 96 + 64 + sl] : 0u;
        float b0 = __uint_as_float(bw << 16);
        float b1 = __uint_as_float(bw & 0xFFFF0000u);
        float ss = A0 * A0 + A1 * A1 + b0 * b0 + b1 * b1;
#pragma unroll
        for (int off = 32; off; off >>= 1) ss += __shfl_xor(ss, off);
        float r = 1.0f / fmaxf(sqrtf(ss), 1e-12f);
        A0 *= r; A1 *= r; b0 *= r; b1 *= r;
        A0 = A0 >= 0.f ? A0 : 0.1f * A0;
        A1 = A1 >= 0.f ? A1 : 0.1f * A1;
        hb32[(size_t)n * 96 + half * 32 + sl] = (uint)f2b(A0) | ((uint)f2b(A1) << 16);
        if (half == 0) {
            b0 = b0 >= 0.f ? b0 : 0.1f * b0;
            b1 = b1 >= 0.f ? b1 : 0.1f * b1;
            hb32[(size_t)n * 96 + 64 + sl] = (uint)f2b(b0) | ((uint)f2b(b1) << 16);
        }
    }
}

// ---------------- decoder ----------------
__global__ __launch_bounds__(128) void m1_kernel(const float* __restrict__ P1,
                                                 const float* __restrict__ P2,
                                                 float* __restrict__ tmpM) {
    int i = blockIdx.x, c = threadIdx.x;
    float s = 0.f;
    for (int k = 0; k < 128; ++k) s += P1[i * 128 + k] * P2[k * 128 + c];
    tmpM[i * 128 + c] = s;
}

__global__ __launch_bounds__(192) void m2_kernel(const float* __restrict__ tmpM,
                                                 const float* __restrict__ P1,
                                                 float* __restrict__ M) {
    __shared__ float trow[128];
    int i = blockIdx.x, j = threadIdx.x;
    if (j < 128) trow[j] = tmpM[i * 128 + j];
    __syncthreads();
    float s = 0.f;
    for (int k = 0; k < 128; ++k) s += trow[k] * P1[j * 128 + k];
    M[i * 192 + j] = s;
}

__global__ __launch_bounds__(192) void decode_kernel(const ushort* __restrict__ hb,
                                                     const int* __restrict__ di,
                                                     const float* __restrict__ M,
                                                     float* __restrict__ out) {
    __shared__ alignas(16) float bvs[8][192];
    __shared__ float red[3][8];
    int pb = blockIdx.x * 8;
    int i = threadIdx.x;
#pragma unroll
    for (int p = 0; p < 8; ++p) {
        int nb = di[(pb + p) * 2 + 1] - 1;
        bvs[p][i] = b2f(hb[(size_t)nb * 192 + i]);
    }
    __syncthreads();
    float t[8] = {};
    const float4* M4 = (const float4*)(M + (size_t)i * 192);
    for (int j4 = 0; j4 < 48; ++j4) {
        float4 m = M4[j4];
#pragma unroll
        for (int p = 0; p < 8; ++p) {
            float4 b = *(const float4*)&bvs[p][j4 * 4];
            t[p] += m.x * b.x + m.y * b.y + m.z * b.z + m.w * b.w;
        }
    }
    int wid = i >> 6, lane = i & 63;
#pragma unroll
    for (int p = 0; p < 8; ++p) {
        int na = di[(pb + p) * 2] - 1;
        float v = b2f(hb[(size_t)na * 192 + i]) * t[p];
#pragma unroll
        for (int off = 32; off; off >>= 1) v += __shfl_xor(v, off);
        if (lane == 0) red[wid][p] = v;
    }
    __syncthreads();
    if (i < 8) out[pb + i] = red[0][i] + red[1][i] + red[2][i];
}

extern "C" void kernel_launch(void* const* d_in, const int* in_sizes, int n_in,
                              void* d_out, int out_size, void* d_ws, size_t ws_size,
                              hipStream_t stream) {
    const float* x     = (const float*)d_in[0];
    const int*   ei    = (const int*)d_in[1];
    const int*   di    = (const int*)d_in[2];
    const float* gamma = (const float*)d_in[3];
    const float* beta  = (const float*)d_in[4];
    const float* Wu[3] = {(const float*)d_in[5], (const float*)d_in[8],  (const float*)d_in[11]};
    const float* Wd[3] = {(const float*)d_in[6], (const float*)d_in[9],  (const float*)d_in[12]};
    const float* Wb[3] = {(const float*)d_in[7], (const float*)d_in[10], (const float*)d_in[13]};
    const float* P1    = (const float*)d_in[14];
    const float* P2    = (const float*)d_in[15];
    float* out = (float*)d_out;
    float* ws  = (float*)d_ws;

    float* bn    = ws + OFF_BN;
    int* gcur  = (int*)(ws + OFF_GCUR);
    int* ccur  = (int*)(ws + OFF_CCUR);
    float* tmpM  = ws + OFF_TMPM;
    float* M     = ws + OFF_M;
    int* woffu = (int*)(ws + OFF_WOFFU);
    int* woffd = (int*)(ws + OFF_WOFFD);
    int* wdegu = (int*)(ws + OFF_WDEGU);
    int* wdegd = (int*)(ws + OFF_WDEGD);
    int* phistu = (int*)(ws + OFF_PHISTU);
    int* phistd = (int*)(ws + OFF_PHISTD);
    ushort* idxu = (ushort*)(ws + OFF_IDXU);
    ushort* idxd = (ushort*)(ws + OFF_IDXD);
    uint* stgu = (uint*)(ws + OFF_STGU);
    uint* stgd = (uint*)(ws + OFF_STGD);
    uint* chk  = (uint*)(ws + OFF_CHK);
    ushort* wb16 = (ushort*)(ws + OFF_WB16);
    ushort* hb   = (ushort*)(ws + OFF_HB);
    ushort* proj = (ushort*)(ws + OFF_PROJ);
    ushort* wbl[3] = {wb16, wb16 + 12288, wb16 + 49152};

    hipMemsetAsync(ws, 0, 336 * sizeof(float), stream);   // bn sums + gcur + ccur

    bn_stats_kernel<<<200, 256, 0, stream>>>(x, bn, PN);
    bn_finalize_kernel<<<1, 64, 0, stream>>>(gamma, beta, bn, PN);

    bin_kernel<<<512, 256, 0, stream>>>(ei, gcur, stgu, stgd, PE);
    rebin_kernel<<<128, 256, 0, stream>>>(stgu, stgd, gcur, ccur, chk);
    hist_kernel<<<64 * NSL2, 256, 0, stream>>>(chk, ccur, phistu, phistd);
    scan_kernel<<<2, 1024, 0, stream>>>(phistu, phistd, woffu, woffd, wdegu, wdegd, (int)L4N);
    scatter_kernel<<<64 * NSL2, 256, 0, stream>>>(chk, ccur, phistu, phistd,
                                                  woffu, woffd, idxu, idxd);

    wconv_kernel<64><<<(192 * 64 + 255) / 256, 256, 0, stream>>>(Wu[0], Wd[0], Wb[0], wbl[0]);
    wconv_kernel<192><<<(192 * 192 + 255) / 256, 256, 0, stream>>>(Wu[1], Wd[1], Wb[1], wbl[1]);
    wconv_kernel<192><<<(192 * 192 + 255) / 256, 256, 0, stream>>>(Wu[2], Wd[2], Wb[2], wbl[2]);

    const int ngb = (PN + 127) / 128;
    gemm_kernel<64, true><<<ngb, 256, 0, stream>>>(hb, x, bn, wbl[0], proj, PN);
    gather_kernel<<<GBLK, 256, 0, stream>>>(proj, woffu, wdegu, woffd, wdegd, idxu, idxd, hb, PN);
    gemm_kernel<192, false><<<ngb, 256, 0, stream>>>(hb, x, bn, wbl[1], proj, PN);
    gather_kernel<<<GBLK, 256, 0, stream>>>(proj, woffu, wdegu, woffd, wdegd, idxu, idxd, hb, PN);
    gemm_kernel<192, false><<<ngb, 256, 0, stream>>>(hb, x, bn, wbl[2], proj, PN);
    gather_kernel<<<GBLK, 256, 0, stream>>>(proj, woffu, wdegu, woffd, wdegd, idxu, idxd, hb, PN);

    m1_kernel<<<192, 128, 0, stream>>>(P1, P2, tmpM);
    m2_kernel<<<192, 192, 0, stream>>>(tmpM, P1, M);
    decode_kernel<<<PB / 8, 192, 0, stream>>>(hb, di, M, out);
}

// Round 13
// 655.202 us; speedup vs baseline: 1.4058x; 1.0676x over previous
//
#include <hip/hip_runtime.h>

#define PN 50000
#define PE 1600000
#define PB 4096
#define NP 8          // dest partitions (XCD-pinned)
#define PSZ 6250      // partition size
#define NSW 4         // source windows
#define SWSZ 12500    // source window size
#define CCAP 60000    // chunk capacity per (partition,dir,window); avg 50K, +44 sigma
#define BCAP 128      // LDS bucket capacity in bin
#define NSL2 4        // slices per chunk for hist/scatter
#define GBLK 2048     // persistent gather blocks (layers 1,2)
#define NPER 7        // nodes per wave: ceil(50000 / (2048*4))
#define GBLK3 512     // gather blocks for layer 3 (di-driven)
#define NPER3 4       // 8192 / (512*4)

typedef __attribute__((ext_vector_type(8))) short bf16x8;
typedef __attribute__((ext_vector_type(4))) float f32x4;
typedef __attribute__((ext_vector_type(8))) unsigned short u16x8;

__device__ inline float b2f(ushort u) {
    union { unsigned int i; float f; } x; x.i = ((unsigned int)u) << 16; return x.f;
}
__device__ inline ushort f2b(float f) {
    union { float f; unsigned int i; } x; x.f = f;
    unsigned int r = (x.i + 0x7FFFu + ((x.i >> 16) & 1u)) >> 16;
    return (ushort)r;
}

// ---------------- workspace layout (in 4-byte words) ----------------
static constexpr size_t L4N = 4 * (size_t)PN;                    // 200000 (node,window) keys
static constexpr size_t IDXCAP = PE + 7 * L4N + 1024;            // ushorts (8-padded + guard)
static constexpr size_t OFF_BN     = 0;                          // 256 f
static constexpr size_t OFF_CCUR   = 256;                        // 64 int
static constexpr size_t OFF_TMPM   = 336;
static constexpr size_t OFF_M      = OFF_TMPM + 192 * 128;
static constexpr size_t OFF_WOFFU  = OFF_M + 192 * 192;          // 4N+4 int
static constexpr size_t OFF_WOFFD  = OFF_WOFFU + L4N + 4;
static constexpr size_t OFF_WDEGU  = OFF_WOFFD + L4N + 4;        // 4N int (true counts)
static constexpr size_t OFF_WDEGD  = OFF_WDEGU + L4N;
static constexpr size_t OFF_PHISTU = OFF_WDEGD + L4N;            // NSL2*4N int
static constexpr size_t OFF_PHISTD = OFF_PHISTU + NSL2 * L4N;
static constexpr size_t OFF_IDXU   = OFF_PHISTD + NSL2 * L4N;    // IDXCAP ushort
static constexpr size_t OFF_IDXD   = OFF_IDXU + (IDXCAP + 1) / 2;
static constexpr size_t OFF_CHK    = OFF_IDXD + (IDXCAP + 1) / 2;    // 64*CCAP u32
static constexpr size_t OFF_WB16   = OFF_CHK + 64 * (size_t)CCAP;    // 43008 words
static constexpr size_t OFF_HB     = OFF_WB16 + 43008;           // N*192 bf16
static constexpr size_t OFF_PROJ   = OFF_HB + (size_t)PN * 96;   // (N+1)*192 bf16 (row PN = zeros)

// ---------------- batchnorm stats ----------------
__global__ __launch_bounds__(256) void bn_stats_kernel(const float* __restrict__ x,
                                                       float* __restrict__ sums, int N) {
    __shared__ float ls[256], ls2[256];
    int col = threadIdx.x & 63;
    int rstart = blockIdx.x * 4 + (threadIdx.x >> 6);
    float s = 0.f, s2 = 0.f;
    for (int r = rstart; r < N; r += gridDim.x * 4) {
        float v = x[(size_t)r * 64 + col];
        s += v; s2 += v * v;
    }
    ls[threadIdx.x] = s; ls2[threadIdx.x] = s2;
    __syncthreads();
    if (threadIdx.x < 64) {
        s  = ls[threadIdx.x]  + ls[threadIdx.x + 64]  + ls[threadIdx.x + 128]  + ls[threadIdx.x + 192];
        s2 = ls2[threadIdx.x] + ls2[threadIdx.x + 64] + ls2[threadIdx.x + 128] + ls2[threadIdx.x + 192];
        atomicAdd(&sums[col], s);
        atomicAdd(&sums[64 + col], s2);
    }
}

__global__ __launch_bounds__(64) void bn_finalize_kernel(const float* __restrict__ gamma,
                                                         const float* __restrict__ beta,
                                                         float* __restrict__ bn, int N) {
    int c = threadIdx.x;
    float mean = bn[c] / (float)N;
    float var = bn[64 + c] / (float)N - mean * mean;
    float sc = gamma[c] * rsqrtf(var + 1e-5f);
    bn[128 + c] = sc;
    bn[192 + c] = beta[c] - mean * sc;
}

// ---------------- CSR1: fused edge binning directly into 64 (p,dir,w) chunks -------------
// chunk id: up = p(c) + 16*w(r); dn = p(r) + 8 + 16*w(c). LDS 64 buckets x BCAP.
__global__ __launch_bounds__(256) void bin_kernel(const int* __restrict__ ei,
                                                  int* __restrict__ ccur,
                                                  uint* __restrict__ chk, int E) {
    __shared__ uint sbuf[64][BCAP];     // 32 KB
    __shared__ int scnt[64], sbase[64];
    const int tid = threadIdx.x;
    for (int base = blockIdx.x * 1024; base < E; base += gridDim.x * 1024) {
        if (tid < 64) scnt[tid] = 0;
        __syncthreads();
#pragma unroll
        for (int j = 0; j < 4; ++j) {
            int e = base + j * 256 + tid;
            if (e < E) {
                int r = __builtin_nontemporal_load(&ei[e]);
                int c = __builtin_nontemporal_load(&ei[E + e]);
                uint uu = ((uint)c << 16) | (uint)r;
                int cu = c / PSZ + 16 * (r / SWSZ);
                int slot = atomicAdd(&scnt[cu], 1);
                if (slot < BCAP) sbuf[cu][slot] = uu;
                else { int pos = atomicAdd(&ccur[cu], 1); if (pos < CCAP) chk[(size_t)cu * CCAP + pos] = uu; }
                uint ud = ((uint)r << 16) | (uint)c;
                int cd = r / PSZ + 8 + 16 * (c / SWSZ);
                int slot2 = atomicAdd(&scnt[cd], 1);
                if (slot2 < BCAP) sbuf[cd][slot2] = ud;
                else { int pos = atomicAdd(&ccur[cd], 1); if (pos < CCAP) chk[(size_t)cd * CCAP + pos] = ud; }
            }
        }
        __syncthreads();
        if (tid < 64) sbase[tid] = atomicAdd(&ccur[tid], min(scnt[tid], BCAP));
        __syncthreads();
#pragma unroll 1
        for (int k = 0; k < 64; ++k) {
            int cnt = min(scnt[k], BCAP);
            int gb = sbase[k];
            uint* dst = chk + (size_t)k * CCAP;
            for (int i = tid; i < cnt; i += 256) {
                int gi = gb + i;
                if (gi < CCAP) dst[gi] = sbuf[k][i];
            }
        }
        __syncthreads();
    }
}

// ---------------- CSR2: per-(chunk,slice) histogram, LDS 25 KB ----------------
__global__ __launch_bounds__(256) void hist_kernel(const uint* __restrict__ chk,
                                                   const int* __restrict__ ccur,
                                                   int* __restrict__ phistu,
                                                   int* __restrict__ phistd) {
    __shared__ int hist[PSZ];           // 25 KB
    const int c = blockIdx.x & 63;
    const int s = blockIdx.x >> 6;
    const int p = c & 7;
    const int dir = (c >> 3) & 1;
    const int w = c >> 4;
    const int tid = threadIdx.x;
    const int lo = p * PSZ;
    for (int i = tid; i < PSZ; i += 256) hist[i] = 0;
    __syncthreads();
    const int cnt = min(ccur[c], CCAP);
    const uint* stg = chk + (size_t)c * CCAP;
    const int per = (cnt + NSL2 - 1) / NSL2;
    const int s0 = s * per, s1 = min(cnt, s0 + per);
    for (int i = s0 + tid; i < s1; i += 256)
        atomicAdd(&hist[(int)(stg[i] >> 16) - lo], 1);
    __syncthreads();
    int* ph = (dir ? phistd : phistu) + (size_t)s * L4N;
    for (int i = tid; i < PSZ; i += 256) ph[(size_t)(lo + i) * NSW + w] = hist[i];
}

// ---------------- scan: wdeg = sum slices; pad to 8; exclusive scan over 4N keys --------
__global__ __launch_bounds__(1024) void scan_kernel(const int* __restrict__ phA,
                                                    const int* __restrict__ phB,
                                                    int* __restrict__ offA,
                                                    int* __restrict__ offB,
                                                    int* __restrict__ degA,
                                                    int* __restrict__ degB, int len) {
    const int* ph = blockIdx.x ? phB : phA;
    int* off = blockIdx.x ? offB : offA;
    int* dego = blockIdx.x ? degB : degA;
    __shared__ int wsum[17];
    int tid = threadIdx.x, lane = tid & 63, wid = tid >> 6;
    int run = 0;
    for (int base = 0; base < len; base += 4096) {
        int i4 = base + tid * 4;
        int4 v = make_int4(0, 0, 0, 0);
        if (i4 < len) {
#pragma unroll
            for (int sl = 0; sl < NSL2; ++sl) {
                int4 t = *(const int4*)&ph[(size_t)sl * len + i4];
                v.x += t.x; v.y += t.y; v.z += t.z; v.w += t.w;
            }
            *(int4*)&dego[i4] = v;
        }
        v.x = (v.x + 7) & ~7; v.y = (v.y + 7) & ~7;
        v.z = (v.z + 7) & ~7; v.w = (v.w + 7) & ~7;
        int lsum = v.x + v.y + v.z + v.w;
        int inc = lsum;
#pragma unroll
        for (int d = 1; d < 64; d <<= 1) {
            int t = __shfl_up(inc, d);
            if (lane >= d) inc += t;
        }
        if (lane == 63) wsum[wid] = inc;
        __syncthreads();
        if (tid == 0) {
            int r2 = 0;
#pragma unroll
            for (int i = 0; i < 16; ++i) { int t = wsum[i]; wsum[i] = r2; r2 += t; }
            wsum[16] = r2;
        }
        __syncthreads();
        if (i4 < len) {
            int pre = run + wsum[wid] + inc - lsum;
            int4 o;
            o.x = pre; o.y = pre + v.x; o.z = o.y + v.y; o.w = o.z + v.z;
            *(int4*)&off[i4] = o;
        }
        run += wsum[16];
        __syncthreads();
    }
    if (tid == 0) off[len] = run;
}

// ---------------- CSR3: per-(chunk,slice) scatter with LDS cursors (25 KB) ----------------
__global__ __launch_bounds__(256) void scatter_kernel(const uint* __restrict__ chk,
                                                      const int* __restrict__ ccur,
                                                      const int* __restrict__ phistu,
                                                      const int* __restrict__ phistd,
                                                      const int* __restrict__ woffu,
                                                      const int* __restrict__ woffd,
                                                      ushort* __restrict__ idxu,
                                                      ushort* __restrict__ idxd) {
    __shared__ int cur[PSZ];            // 25 KB
    const int c = blockIdx.x & 63;
    const int s = blockIdx.x >> 6;
    const int p = c & 7;
    const int dir = (c >> 3) & 1;
    const int w = c >> 4;
    const int tid = threadIdx.x;
    const int lo = p * PSZ;
    const int* woff = (dir ? woffd : woffu);
    const int* phist = (dir ? phistd : phistu);
    for (int i = tid; i < PSZ; i += 256) {
        size_t key = (size_t)(lo + i) * NSW + w;
        int cv = woff[key];
        for (int t = 0; t < s; ++t) cv += phist[(size_t)t * L4N + key];
        cur[i] = cv;
    }
    __syncthreads();
    const int cnt = min(ccur[c], CCAP);
    const uint* stg = chk + (size_t)c * CCAP;
    ushort* idx = (dir ? idxd : idxu);
    const int per = (cnt + NSL2 - 1) / NSL2;
    const int s0 = s * per, s1 = min(cnt, s0 + per);
    for (int i = s0 + tid; i < s1; i += 256) {
        uint u = stg[i];
        int pos = atomicAdd(&cur[(int)(u >> 16) - lo], 1);
        idx[pos] = (ushort)(u & 0xFFFFu);
    }
}

// ---------------- pad fill: sentinel src=PN in [off+deg, off+pad8) ----------------
__global__ __launch_bounds__(256) void padfill_kernel(const int* __restrict__ woffu,
                                                      const int* __restrict__ wdegu,
                                                      const int* __restrict__ woffd,
                                                      const int* __restrict__ wdegd,
                                                      ushort* __restrict__ idxu,
                                                      ushort* __restrict__ idxd) {
    int k = blockIdx.x * 256 + threadIdx.x;
    int half = (k >= (int)L4N);
    if (half) k -= (int)L4N;
    if (k >= (int)L4N) return;
    const int* woff = half ? woffd : woffu;
    const int* wdeg = half ? wdegd : wdegu;
    ushort* idx = half ? idxd : idxu;
    int off = woff[k], d = wdeg[k], pe = (d + 7) & ~7;
    for (int i = d; i < pe; ++i) idx[off + i] = (ushort)PN;
}

// ---------------- weight convert ----------------
template<int K>
__global__ __launch_bounds__(256) void wconv_kernel(const float* __restrict__ Wu,
                                                    const float* __restrict__ Wd,
                                                    const float* __restrict__ Wb,
                                                    ushort* __restrict__ out) {
    int idx = blockIdx.x * 256 + threadIdx.x;
    if (idx >= 192 * K) return;
    int c = idx / K, k = idx - c * K;
    const float* W = (c < 64) ? Wu : (c < 128 ? Wd : Wb);
    out[idx] = f2b(W[k * 64 + (c & 63)]);
}

// ---------------- MFMA GEMM: proj[N,192] = A[N,K] @ W[K,192] ----------------
template<int K, bool BN>
__global__ __launch_bounds__(256) void gemm_kernel(const ushort* __restrict__ hb,
                                                   const float* __restrict__ x,
                                                   const float* __restrict__ bn,
                                                   const ushort* __restrict__ wb,
                                                   ushort* __restrict__ proj, int nrows) {
    constexpr int KP = K + 8;
    __shared__ ushort wlds[192 * KP];
    const int tid = threadIdx.x;
    constexpr int KB8 = K / 8;
    for (int idx = tid; idx < 192 * KB8; idx += 256) {
        int col = idx / KB8, kb = idx - col * KB8;
        *(bf16x8*)&wlds[col * KP + kb * 8] = *(const bf16x8*)&wb[(size_t)col * K + kb * 8];
    }
    __syncthreads();
    const int lane = tid & 63, wid = tid >> 6;
    const int kgrp = (lane >> 4) * 8;
    const int rbase = blockIdx.x * 128 + wid * 32;
    int ar[2] = { min(rbase + (lane & 15), nrows - 1),
                  min(rbase + 16 + (lane & 15), nrows - 1) };
    f32x4 acc[2][12];
#pragma unroll
    for (int rt = 0; rt < 2; ++rt)
#pragma unroll
        for (int ct = 0; ct < 12; ++ct) acc[rt][ct] = (f32x4)0.0f;

#pragma unroll
    for (int k0 = 0; k0 < K; k0 += 32) {
        bf16x8 af[2];
        if (BN) {
#pragma unroll
            for (int rt = 0; rt < 2; ++rt)
#pragma unroll
                for (int j = 0; j < 8; ++j) {
                    int c = k0 + kgrp + j;
                    float v = x[(size_t)ar[rt] * 64 + c] * bn[128 + c] + bn[192 + c];
                    af[rt][j] = (short)f2b(v);
                }
        } else {
#pragma unroll
            for (int rt = 0; rt < 2; ++rt)
                af[rt] = *(const bf16x8*)&hb[(size_t)ar[rt] * 192 + k0 + kgrp];
        }
#pragma unroll
        for (int ct = 0; ct < 12; ++ct) {
            bf16x8 bfr = *(const bf16x8*)&wlds[(ct * 16 + (lane & 15)) * KP + k0 + kgrp];
            acc[0][ct] = __builtin_amdgcn_mfma_f32_16x16x32_bf16(af[0], bfr, acc[0][ct], 0, 0, 0);
            acc[1][ct] = __builtin_amdgcn_mfma_f32_16x16x32_bf16(af[1], bfr, acc[1][ct], 0, 0, 0);
        }
    }
    const int orow0 = blockIdx.x * 128 + wid * 32 + (lane >> 4) * 4;
#pragma unroll
    for (int rt = 0; rt < 2; ++rt)
#pragma unroll
        for (int ct = 0; ct < 12; ++ct) {
            int ocol = ct * 16 + (lane & 15);
#pragma unroll
            for (int j = 0; j < 4; ++j) {
                int orow = orow0 + rt * 16 + j;
                if (orow < nrows) proj[(size_t)orow * 192 + ocol] = f2b(acc[rt][ct][j]);
            }
        }
}

// ---------------- persistent windowed gather + normalize + leaky ----------------
// Sentinel-padded segments: inner loop is branch-free, 8 rows in flight.
// DI=false: node = gw + j*nwaves (all N). DI=true: node = di[gw + j*nwaves]-1 (decode set).
template<int NPERT, bool DI>
__global__ __launch_bounds__(256) void gather_kernel(const ushort* __restrict__ proj,
                                                     const int* __restrict__ woffu,
                                                     const int* __restrict__ wdegu,
                                                     const int* __restrict__ woffd,
                                                     const int* __restrict__ wdegd,
                                                     const ushort* __restrict__ idxu,
                                                     const ushort* __restrict__ idxd,
                                                     const int* __restrict__ di,
                                                     ushort* __restrict__ hb, int N) {
    const int gw = blockIdx.x * 4 + (threadIdx.x >> 6);
    const int nwaves = gridDim.x * 4;
    const int lane = threadIdx.x & 63;
    const int half = lane >> 5;          // 0 = up, 1 = dn
    const int sl = lane & 31;
    const int* __restrict__ woff = half ? woffd : woffu;
    const int* __restrict__ wdeg = half ? wdegd : wdegu;
    const ushort* __restrict__ idx = half ? idxd : idxu;
    const uint* __restrict__ rowb = (const uint*)proj + half * 32 + sl;

    int nn[NPERT];
#pragma unroll
    for (int j = 0; j < NPERT; ++j) {
        int k = gw + j * nwaves;
        nn[j] = DI ? (k < 2 * PB ? di[k] - 1 : -1) : (k < N ? k : -1);
    }
    float a0[NPERT], a1[NPERT];
    int dtot[NPERT];
#pragma unroll
    for (int j = 0; j < NPERT; ++j) { a0[j] = 0.f; a1[j] = 0.f; dtot[j] = 0; }

    for (int w = 0; w < NSW; ++w) {
#pragma unroll
        for (int j = 0; j < NPERT; ++j) {
            int n = nn[j];
            if (n >= 0) {
                int key = n * NSW + w;
                int s = woff[key];
                int cnt = wdeg[key];
                dtot[j] += cnt;
                int cntp = (cnt + 7) & ~7;
                const ushort* p = idx + s;
                for (int i = 0; i < cntp; i += 8) {
                    u16x8 U = *(const u16x8*)(p + i);
                    uint w0 = rowb[(size_t)U[0] * 96];
                    uint w1 = rowb[(size_t)U[1] * 96];
                    uint w2 = rowb[(size_t)U[2] * 96];
                    uint w3 = rowb[(size_t)U[3] * 96];
                    uint w4 = rowb[(size_t)U[4] * 96];
                    uint w5 = rowb[(size_t)U[5] * 96];
                    uint w6 = rowb[(size_t)U[6] * 96];
                    uint w7 = rowb[(size_t)U[7] * 96];
                    a0[j] += (__uint_as_float(w0 << 16) + __uint_as_float(w1 << 16))
                           + (__uint_as_float(w2 << 16) + __uint_as_float(w3 << 16))
                           + (__uint_as_float(w4 << 16) + __uint_as_float(w5 << 16))
                           + (__uint_as_float(w6 << 16) + __uint_as_float(w7 << 16));
                    a1[j] += (__uint_as_float(w0 & 0xFFFF0000u) + __uint_as_float(w1 & 0xFFFF0000u))
                           + (__uint_as_float(w2 & 0xFFFF0000u) + __uint_as_float(w3 & 0xFFFF0000u))
                           + (__uint_as_float(w4 & 0xFFFF0000u) + __uint_as_float(w5 & 0xFFFF0000u))
                           + (__uint_as_float(w6 & 0xFFFF0000u) + __uint_as_float(w7 & 0xFFFF0000u));
                }
            }
        }
        __syncthreads();   // keep the block's 4 waves in phase
    }

    uint* hb32 = (uint*)hb;
#pragma unroll
    for (int j = 0; j < NPERT; ++j) {
        int n = nn[j];
        if (n < 0) continue;
        float sc = 1.0f / (float)max(dtot[j], 1);
        float A0 = a0[j] * sc, A1 = a1[j] * sc;
        uint bw = (half == 0) ? ((const uint*)proj)[(size_t)n * 96 + 64 + sl] : 0u;
        float b0 = __uint_as_float(bw << 16);
        float b1 = __uint_as_float(bw & 0xFFFF0000u);
        float ss = A0 * A0 + A1 * A1 + b0 * b0 + b1 * b1;
#pragma unroll
        for (int off = 32; off; off >>= 1) ss += __shfl_xor(ss, off);
        float r = 1.0f / fmaxf(sqrtf(ss), 1e-12f);
        A0 *= r; A1 *= r; b0 *= r; b1 *= r;
        A0 = A0 >= 0.f ? A0 : 0.1f * A0;
        A1 = A1 >= 0.f ? A1 : 0.1f * A1;
        hb32[(size_t)n * 96 + half * 32 + sl] = (uint)f2b(A0) | ((uint)f2b(A1) << 16);
        if (half == 0) {
            b0 = b0 >= 0.f ? b0 : 0.1f * b0;
            b1 = b1 >= 0.f ? b1 : 0.1f * b1;
            hb32[(size_t)n * 96 + 64 + sl] = (uint)f2b(b0) | ((uint)f2b(b1) << 16);
        }
    }
}

// ---------------- decoder ----------------
__global__ __launch_bounds__(128) void m1_kernel(const float* __restrict__ P1,
                                                 const float* __restrict__ P2,
                                                 float* __restrict__ tmpM) {
    int i = blockIdx.x, c = threadIdx.x;
    float s = 0.f;
    for (int k = 0; k < 128; ++k) s += P1[i * 128 + k] * P2[k * 128 + c];
    tmpM[i * 128 + c] = s;
}

__global__ __launch_bounds__(192) void m2_kernel(const float* __restrict__ tmpM,
                                                 const float* __restrict__ P1,
                                                 float* __restrict__ M) {
    __shared__ float trow[128];
    int i = blockIdx.x, j = threadIdx.x;
    if (j < 128) trow[j] = tmpM[i * 128 + j];
    __syncthreads();
    float s = 0.f;
    for (int k = 0; k < 128; ++k) s += trow[k] * P1[j * 128 + k];
    M[i * 192 + j] = s;
}

__global__ __launch_bounds__(192) void decode_kernel(const ushort* __restrict__ hb,
                                                     const int* __restrict__ di,
                                                     const float* __restrict__ M,
                                                     float* __restrict__ out) {
    __shared__ alignas(16) float bvs[8][192];
    __shared__ float red[3][8];
    int pb = blockIdx.x * 8;
    int i = threadIdx.x;
#pragma unroll
    for (int p = 0; p < 8; ++p) {
        int nb = di[(pb + p) * 2 + 1] - 1;
        bvs[p][i] = b2f(hb[(size_t)nb * 192 + i]);
    }
    __syncthreads();
    float t[8] = {};
    const float4* M4 = (const float4*)(M + (size_t)i * 192);
    for (int j4 = 0; j4 < 48; ++j4) {
        float4 m = M4[j4];
#pragma unroll
        for (int p = 0; p < 8; ++p) {
            float4 b = *(const float4*)&bvs[p][j4 * 4];
            t[p] += m.x * b.x + m.y * b.y + m.z * b.z + m.w * b.w;
        }
    }
    int wid = i >> 6, lane = i & 63;
#pragma unroll
    for (int p = 0; p < 8; ++p) {
        int na = di[(pb + p) * 2] - 1;
        float v = b2f(hb[(size_t)na * 192 + i]) * t[p];
#pragma unroll
        for (int off = 32; off; off >>= 1) v += __shfl_xor(v, off);
        if (lane == 0) red[wid][p] = v;
    }
    __syncthreads();
    if (i < 8) out[pb + i] = red[0][i] + red[1][i] + red[2][i];
}

extern "C" void kernel_launch(void* const* d_in, const int* in_sizes, int n_in,
                              void* d_out, int out_size, void* d_ws, size_t ws_size,
                              hipStream_t stream) {
    const float* x     = (const float*)d_in[0];
    const int*   ei    = (const int*)d_in[1];
    const int*   di    = (const int*)d_in[2];
    const float* gamma = (const float*)d_in[3];
    const float* beta  = (const float*)d_in[4];
    const float* Wu[3] = {(const float*)d_in[5], (const float*)d_in[8],  (const float*)d_in[11]};
    const float* Wd[3] = {(const float*)d_in[6], (const float*)d_in[9],  (const float*)d_in[12]};
    const float* Wb[3] = {(const float*)d_in[7], (const float*)d_in[10], (const float*)d_in[13]};
    const float* P1    = (const float*)d_in[14];
    const float* P2    = (const float*)d_in[15];
    float* out = (float*)d_out;
    float* ws  = (float*)d_ws;

    float* bn    = ws + OFF_BN;
    int* ccur  = (int*)(ws + OFF_CCUR);
    float* tmpM  = ws + OFF_TMPM;
    float* M     = ws + OFF_M;
    int* woffu = (int*)(ws + OFF_WOFFU);
    int* woffd = (int*)(ws + OFF_WOFFD);
    int* wdegu = (int*)(ws + OFF_WDEGU);
    int* wdegd = (int*)(ws + OFF_WDEGD);
    int* phistu = (int*)(ws + OFF_PHISTU);
    int* phistd = (int*)(ws + OFF_PHISTD);
    ushort* idxu = (ushort*)(ws + OFF_IDXU);
    ushort* idxd = (ushort*)(ws + OFF_IDXD);
    uint* chk  = (uint*)(ws + OFF_CHK);
    ushort* wb16 = (ushort*)(ws + OFF_WB16);
    ushort* hb   = (ushort*)(ws + OFF_HB);
    ushort* proj = (ushort*)(ws + OFF_PROJ);
    ushort* wbl[3] = {wb16, wb16 + 12288, wb16 + 49152};

    hipMemsetAsync(ws, 0, 336 * sizeof(float), stream);          // bn sums + ccur
    hipMemsetAsync(proj + (size_t)PN * 192, 0, 384, stream);     // sentinel row PN = zeros

    bn_stats_kernel<<<200, 256, 0, stream>>>(x, bn, PN);
    bn_finalize_kernel<<<1, 64, 0, stream>>>(gamma, beta, bn, PN);

    bin_kernel<<<512, 256, 0, stream>>>(ei, ccur, chk, PE);
    hist_kernel<<<64 * NSL2, 256, 0, stream>>>(chk, ccur, phistu, phistd);
    scan_kernel<<<2, 1024, 0, stream>>>(phistu, phistd, woffu, woffd, wdegu, wdegd, (int)L4N);
    scatter_kernel<<<64 * NSL2, 256, 0, stream>>>(chk, ccur, phistu, phistd,
                                                  woffu, woffd, idxu, idxd);
    padfill_kernel<<<(2 * (int)L4N + 255) / 256, 256, 0, stream>>>(woffu, wdegu, woffd, wdegd,
                                                                   idxu, idxd);

    wconv_kernel<64><<<(192 * 64 + 255) / 256, 256, 0, stream>>>(Wu[0], Wd[0], Wb[0], wbl[0]);
    wconv_kernel<192><<<(192 * 192 + 255) / 256, 256, 0, stream>>>(Wu[1], Wd[1], Wb[1], wbl[1]);
    wconv_kernel<192><<<(192 * 192 + 255) / 256, 256, 0, stream>>>(Wu[2], Wd[2], Wb[2], wbl[2]);

    const int ngb = (PN + 127) / 128;
    gemm_kernel<64, true><<<ngb, 256, 0, stream>>>(hb, x, bn, wbl[0], proj, PN);
    gather_kernel<NPER, false><<<GBLK, 256, 0, stream>>>(proj, woffu, wdegu, woffd, wdegd,
                                                         idxu, idxd, di, hb, PN);
    gemm_kernel<192, false><<<ngb, 256, 0, stream>>>(hb, x, bn, wbl[1], proj, PN);
    gather_kernel<NPER, false><<<GBLK, 256, 0, stream>>>(proj, woffu, wdegu, woffd, wdegd,
                                                         idxu, idxd, di, hb, PN);
    gemm_kernel<192, false><<<ngb, 256, 0, stream>>>(hb, x, bn, wbl[2], proj, PN);
    gather_kernel<NPER3, true><<<GBLK3, 256, 0, stream>>>(proj, woffu, wdegu, woffd, wdegd,
                                                          idxu, idxd, di, hb, PN);

    m1_kernel<<<192, 128, 0, stream>>>(P1, P2, tmpM);
    m2_kernel<<<192, 192, 0, stream>>>(tmpM, P1, M);
    decode_kernel<<<PB / 8, 192, 0, stream>>>(hb, di, M, out);
}

// Round 15
// 615.434 us; speedup vs baseline: 1.4967x; 1.0646x over previous
//
#include <hip/hip_runtime.h>

#define PN 50000
#define PE 1600000
#define PB 4096
#define NP 8          // dest partitions (XCD-pinned)
#define PSZ 6250      // partition size
#define NSW 4         // source windows
#define SWSZ 12500    // source window size
#define CCAP 60000    // chunk capacity per (partition,dir,window); avg 50K
#define BCAP 128      // LDS bucket capacity in bin
#define NSL2 4        // slices per chunk for hist/scatter
#define GBLK 2048     // persistent gather blocks (layers 1,2)
#define NPER 7        // nodes per wave: ceil(50000 / (2048*4))
#define GBLK3 512     // gather blocks for layer 3 (di-driven)
#define NPER3 4       // 8192 / (512*4)

typedef __attribute__((ext_vector_type(8))) short bf16x8;
typedef __attribute__((ext_vector_type(4))) float f32x4;

__device__ inline float b2f(ushort u) {
    union { unsigned int i; float f; } x; x.i = ((unsigned int)u) << 16; return x.f;
}
__device__ inline ushort f2b(float f) {
    union { float f; unsigned int i; } x; x.f = f;
    unsigned int r = (x.i + 0x7FFFu + ((x.i >> 16) & 1u)) >> 16;
    return (ushort)r;
}

// ---------------- workspace layout (in 4-byte words) ----------------
static constexpr size_t L4N = 4 * (size_t)PN;                    // 200000 (node,window) keys
static constexpr size_t IDXCAP = PE + 3 * L4N + 1024;            // ushorts (4-padded + guard)
static constexpr size_t OFF_BN     = 0;                          // 256 f
static constexpr size_t OFF_CCUR   = 256;                        // 64 int
static constexpr size_t OFF_TMPM   = 336;
static constexpr size_t OFF_M      = OFF_TMPM + 192 * 128;
static constexpr size_t OFF_WOFFU  = OFF_M + 192 * 192;          // 4N+4 int
static constexpr size_t OFF_WOFFD  = OFF_WOFFU + L4N + 4;
static constexpr size_t OFF_WDEGU  = OFF_WOFFD + L4N + 4;        // 4N int (true counts)
static constexpr size_t OFF_WDEGD  = OFF_WDEGU + L4N;
static constexpr size_t OFF_PHISTU = OFF_WDEGD + L4N;            // NSL2*4N int
static constexpr size_t OFF_PHISTD = OFF_PHISTU + NSL2 * L4N;
static constexpr size_t OFF_IDXU   = OFF_PHISTD + NSL2 * L4N;    // IDXCAP ushort
static constexpr size_t OFF_IDXD   = OFF_IDXU + (IDXCAP + 1) / 2;
static constexpr size_t OFF_CHK    = OFF_IDXD + (IDXCAP + 1) / 2;    // 64*CCAP u32
static constexpr size_t OFF_WB16   = OFF_CHK + 64 * (size_t)CCAP;    // 43008 words
static constexpr size_t OFF_HB     = OFF_WB16 + 43008;           // N*192 bf16
static constexpr size_t OFF_PROJ   = OFF_HB + (size_t)PN * 96;   // N*192 bf16

// ---------------- batchnorm stats ----------------
__global__ __launch_bounds__(256) void bn_stats_kernel(const float* __restrict__ x,
                                                       float* __restrict__ sums, int N) {
    __shared__ float ls[256], ls2[256];
    int col = threadIdx.x & 63;
    int rstart = blockIdx.x * 4 + (threadIdx.x >> 6);
    float s = 0.f, s2 = 0.f;
    for (int r = rstart; r < N; r += gridDim.x * 4) {
        float v = x[(size_t)r * 64 + col];
        s += v; s2 += v * v;
    }
    ls[threadIdx.x] = s; ls2[threadIdx.x] = s2;
    __syncthreads();
    if (threadIdx.x < 64) {
        s  = ls[threadIdx.x]  + ls[threadIdx.x + 64]  + ls[threadIdx.x + 128]  + ls[threadIdx.x + 192];
        s2 = ls2[threadIdx.x] + ls2[threadIdx.x + 64] + ls2[threadIdx.x + 128] + ls2[threadIdx.x + 192];
        atomicAdd(&sums[col], s);
        atomicAdd(&sums[64 + col], s2);
    }
}

__global__ __launch_bounds__(64) void bn_finalize_kernel(const float* __restrict__ gamma,
                                                         const float* __restrict__ beta,
                                                         float* __restrict__ bn, int N) {
    int c = threadIdx.x;
    float mean = bn[c] / (float)N;
    float var = bn[64 + c] / (float)N - mean * mean;
    float sc = gamma[c] * rsqrtf(var + 1e-5f);
    bn[128 + c] = sc;
    bn[192 + c] = beta[c] - mean * sc;
}

// ---------------- CSR1: fused edge binning directly into 64 (p,dir,w) chunks -------------
__global__ __launch_bounds__(256) void bin_kernel(const int* __restrict__ ei,
                                                  int* __restrict__ ccur,
                                                  uint* __restrict__ chk, int E) {
    __shared__ uint sbuf[64][BCAP];     // 32 KB
    __shared__ int scnt[64], sbase[64];
    const int tid = threadIdx.x;
    for (int base = blockIdx.x * 1024; base < E; base += gridDim.x * 1024) {
        if (tid < 64) scnt[tid] = 0;
        __syncthreads();
#pragma unroll
        for (int j = 0; j < 4; ++j) {
            int e = base + j * 256 + tid;
            if (e < E) {
                int r = __builtin_nontemporal_load(&ei[e]);
                int c = __builtin_nontemporal_load(&ei[E + e]);
                uint uu = ((uint)c << 16) | (uint)r;
                int cu = c / PSZ + 16 * (r / SWSZ);
                int slot = atomicAdd(&scnt[cu], 1);
                if (slot < BCAP) sbuf[cu][slot] = uu;
                else { int pos = atomicAdd(&ccur[cu], 1); if (pos < CCAP) chk[(size_t)cu * CCAP + pos] = uu; }
                uint ud = ((uint)r << 16) | (uint)c;
                int cd = r / PSZ + 8 + 16 * (c / SWSZ);
                int slot2 = atomicAdd(&scnt[cd], 1);
                if (slot2 < BCAP) sbuf[cd][slot2] = ud;
                else { int pos = atomicAdd(&ccur[cd], 1); if (pos < CCAP) chk[(size_t)cd * CCAP + pos] = ud; }
            }
        }
        __syncthreads();
        if (tid < 64) sbase[tid] = atomicAdd(&ccur[tid], min(scnt[tid], BCAP));
        __syncthreads();
#pragma unroll 1
        for (int k = 0; k < 64; ++k) {
            int cnt = min(scnt[k], BCAP);
            int gb = sbase[k];
            uint* dst = chk + (size_t)k * CCAP;
            for (int i = tid; i < cnt; i += 256) {
                int gi = gb + i;
                if (gi < CCAP) dst[gi] = sbuf[k][i];
            }
        }
        __syncthreads();
    }
}

// ---------------- CSR2: per-(chunk,slice) histogram, LDS 25 KB ----------------
__global__ __launch_bounds__(256) void hist_kernel(const uint* __restrict__ chk,
                                                   const int* __restrict__ ccur,
                                                   int* __restrict__ phistu,
                                                   int* __restrict__ phistd) {
    __shared__ int hist[PSZ];           // 25 KB
    const int c = blockIdx.x & 63;
    const int s = blockIdx.x >> 6;
    const int p = c & 7;
    const int dir = (c >> 3) & 1;
    const int w = c >> 4;
    const int tid = threadIdx.x;
    const int lo = p * PSZ;
    for (int i = tid; i < PSZ; i += 256) hist[i] = 0;
    __syncthreads();
    const int cnt = min(ccur[c], CCAP);
    const uint* stg = chk + (size_t)c * CCAP;
    const int per = (cnt + NSL2 - 1) / NSL2;
    const int s0 = s * per, s1 = min(cnt, s0 + per);
    for (int i = s0 + tid; i < s1; i += 256)
        atomicAdd(&hist[(int)(stg[i] >> 16) - lo], 1);
    __syncthreads();
    int* ph = (dir ? phistd : phistu) + (size_t)s * L4N;
    for (int i = tid; i < PSZ; i += 256) ph[(size_t)(lo + i) * NSW + w] = hist[i];
}

// ---------------- scan: wdeg = sum slices; pad to 4; exclusive scan over 4N keys --------
__global__ __launch_bounds__(1024) void scan_kernel(const int* __restrict__ phA,
                                                    const int* __restrict__ phB,
                                                    int* __restrict__ offA,
                                                    int* __restrict__ offB,
                                                    int* __restrict__ degA,
                                                    int* __restrict__ degB, int len) {
    const int* ph = blockIdx.x ? phB : phA;
    int* off = blockIdx.x ? offB : offA;
    int* dego = blockIdx.x ? degB : degA;
    __shared__ int wsum[17];
    int tid = threadIdx.x, lane = tid & 63, wid = tid >> 6;
    int run = 0;
    for (int base = 0; base < len; base += 4096) {
        int i4 = base + tid * 4;
        int4 v = make_int4(0, 0, 0, 0);
        if (i4 < len) {
#pragma unroll
            for (int sl = 0; sl < NSL2; ++sl) {
                int4 t = *(const int4*)&ph[(size_t)sl * len + i4];
                v.x += t.x; v.y += t.y; v.z += t.z; v.w += t.w;
            }
            *(int4*)&dego[i4] = v;
        }
        v.x = (v.x + 3) & ~3; v.y = (v.y + 3) & ~3;
        v.z = (v.z + 3) & ~3; v.w = (v.w + 3) & ~3;
        int lsum = v.x + v.y + v.z + v.w;
        int inc = lsum;
#pragma unroll
        for (int d = 1; d < 64; d <<= 1) {
            int t = __shfl_up(inc, d);
            if (lane >= d) inc += t;
        }
        if (lane == 63) wsum[wid] = inc;
        __syncthreads();
        if (tid == 0) {
            int r2 = 0;
#pragma unroll
            for (int i = 0; i < 16; ++i) { int t = wsum[i]; wsum[i] = r2; r2 += t; }
            wsum[16] = r2;
        }
        __syncthreads();
        if (i4 < len) {
            int pre = run + wsum[wid] + inc - lsum;
            int4 o;
            o.x = pre; o.y = pre + v.x; o.z = o.y + v.y; o.w = o.z + v.z;
            *(int4*)&off[i4] = o;
        }
        run += wsum[16];
        __syncthreads();
    }
    if (tid == 0) off[len] = run;
}

// ---------------- CSR3: per-(chunk,slice) scatter with LDS cursors (25 KB) ----------------
__global__ __launch_bounds__(256) void scatter_kernel(const uint* __restrict__ chk,
                                                      const int* __restrict__ ccur,
                                                      const int* __restrict__ phistu,
                                                      const int* __restrict__ phistd,
                                                      const int* __restrict__ woffu,
                                                      const int* __restrict__ woffd,
                                                      ushort* __restrict__ idxu,
                                                      ushort* __restrict__ idxd) {
    __shared__ int cur[PSZ];            // 25 KB
    const int c = blockIdx.x & 63;
    const int s = blockIdx.x >> 6;
    const int p = c & 7;
    const int dir = (c >> 3) & 1;
    const int w = c >> 4;
    const int tid = threadIdx.x;
    const int lo = p * PSZ;
    const int* woff = (dir ? woffd : woffu);
    const int* phist = (dir ? phistd : phistu);
    for (int i = tid; i < PSZ; i += 256) {
        size_t key = (size_t)(lo + i) * NSW + w;
        int cv = woff[key];
        for (int t = 0; t < s; ++t) cv += phist[(size_t)t * L4N + key];
        cur[i] = cv;
    }
    __syncthreads();
    const int cnt = min(ccur[c], CCAP);
    const uint* stg = chk + (size_t)c * CCAP;
    ushort* idx = (dir ? idxd : idxu);
    const int per = (cnt + NSL2 - 1) / NSL2;
    const int s0 = s * per, s1 = min(cnt, s0 + per);
    for (int i = s0 + tid; i < s1; i += 256) {
        uint u = stg[i];
        int pos = atomicAdd(&cur[(int)(u >> 16) - lo], 1);
        idx[pos] = (ushort)(u & 0xFFFFu);
    }
}

// ---------------- weight convert ----------------
template<int K>
__global__ __launch_bounds__(256) void wconv_kernel(const float* __restrict__ Wu,
                                                    const float* __restrict__ Wd,
                                                    const float* __restrict__ Wb,
                                                    ushort* __restrict__ out) {
    int idx = blockIdx.x * 256 + threadIdx.x;
    if (idx >= 192 * K) return;
    int c = idx / K, k = idx - c * K;
    const float* W = (c < 64) ? Wu : (c < 128 ? Wd : Wb);
    out[idx] = f2b(W[k * 64 + (c & 63)]);
}

// ---------------- MFMA GEMM: proj[N,192] = A[N,K] @ W[K,192] ----------------
template<int K, bool BN>
__global__ __launch_bounds__(256) void gemm_kernel(const ushort* __restrict__ hb,
                                                   const float* __restrict__ x,
                                                   const float* __restrict__ bn,
                                                   const ushort* __restrict__ wb,
                                                   ushort* __restrict__ proj, int nrows) {
    constexpr int KP = K + 8;
    __shared__ ushort wlds[192 * KP];
    const int tid = threadIdx.x;
    constexpr int KB8 = K / 8;
    for (int idx = tid; idx < 192 * KB8; idx += 256) {
        int col = idx / KB8, kb = idx - col * KB8;
        *(bf16x8*)&wlds[col * KP + kb * 8] = *(const bf16x8*)&wb[(size_t)col * K + kb * 8];
    }
    __syncthreads();
    const int lane = tid & 63, wid = tid >> 6;
    const int kgrp = (lane >> 4) * 8;
    const int rbase = blockIdx.x * 128 + wid * 32;
    int ar[2] = { min(rbase + (lane & 15), nrows - 1),
                  min(rbase + 16 + (lane & 15), nrows - 1) };
    f32x4 acc[2][12];
#pragma unroll
    for (int rt = 0; rt < 2; ++rt)
#pragma unroll
        for (int ct = 0; ct < 12; ++ct) acc[rt][ct] = (f32x4)0.0f;

#pragma unroll
    for (int k0 = 0; k0 < K; k0 += 32) {
        bf16x8 af[2];
        if (BN) {
#pragma unroll
            for (int rt = 0; rt < 2; ++rt)
#pragma unroll
                for (int j = 0; j < 8; ++j) {
                    int c = k0 + kgrp + j;
                    float v = x[(size_t)ar[rt] * 64 + c] * bn[128 + c] + bn[192 + c];
                    af[rt][j] = (short)f2b(v);
                }
        } else {
#pragma unroll
            for (int rt = 0; rt < 2; ++rt)
                af[rt] = *(const bf16x8*)&hb[(size_t)ar[rt] * 192 + k0 + kgrp];
        }
#pragma unroll
        for (int ct = 0; ct < 12; ++ct) {
            bf16x8 bfr = *(const bf16x8*)&wlds[(ct * 16 + (lane & 15)) * KP + k0 + kgrp];
            acc[0][ct] = __builtin_amdgcn_mfma_f32_16x16x32_bf16(af[0], bfr, acc[0][ct], 0, 0, 0);
            acc[1][ct] = __builtin_amdgcn_mfma_f32_16x16x32_bf16(af[1], bfr, acc[1][ct], 0, 0, 0);
        }
    }
    const int orow0 = blockIdx.x * 128 + wid * 32 + (lane >> 4) * 4;
#pragma unroll
    for (int rt = 0; rt < 2; ++rt)
#pragma unroll
        for (int ct = 0; ct < 12; ++ct) {
            int ocol = ct * 16 + (lane & 15);
#pragma unroll
            for (int j = 0; j < 4; ++j) {
                int orow = orow0 + rt * 16 + j;
                if (orow < nrows) proj[(size_t)orow * 192 + ocol] = f2b(acc[rt][ct][j]);
            }
        }
}

// ---------------- persistent windowed gather + normalize + leaky ----------------
// 4-wide masked inner loop (R11-proven). DI=false: node = gw + j*nwaves (all N).
// DI=true: node = di[gw + j*nwaves]-1 (decode set only).
template<int NPERT, bool DI>
__global__ __launch_bounds__(256) void gather_kernel(const ushort* __restrict__ proj,
                                                     const int* __restrict__ woffu,
                                                     const int* __restrict__ wdegu,
                                                     const int* __restrict__ woffd,
                                                     const int* __restrict__ wdegd,
                                                     const ushort* __restrict__ idxu,
                                                     const ushort* __restrict__ idxd,
                                                     const int* __restrict__ di,
                                                     ushort* __restrict__ hb, int N) {
    const int gw = blockIdx.x * 4 + (threadIdx.x >> 6);
    const int nwaves = gridDim.x * 4;
    const int lane = threadIdx.x & 63;
    const int half = lane >> 5;          // 0 = up, 1 = dn
    const int sl = lane & 31;
    const int* __restrict__ woff = half ? woffd : woffu;
    const int* __restrict__ wdeg = half ? wdegd : wdegu;
    const ushort* __restrict__ idx = half ? idxd : idxu;
    const uint* __restrict__ rowb = (const uint*)proj + half * 32 + sl;

    int nn[NPERT];
#pragma unroll
    for (int j = 0; j < NPERT; ++j) {
        int k = gw + j * nwaves;
        nn[j] = DI ? (k < 2 * PB ? di[k] - 1 : -1) : (k < N ? k : -1);
    }
    float a0[NPERT], a1[NPERT];
    int dtot[NPERT];
#pragma unroll
    for (int j = 0; j < NPERT; ++j) { a0[j] = 0.f; a1[j] = 0.f; dtot[j] = 0; }

    for (int w = 0; w < NSW; ++w) {
#pragma unroll
        for (int j = 0; j < NPERT; ++j) {
            int n = nn[j];
            if (n >= 0) {
                int key = n * NSW + w;
                int s = woff[key];
                int cnt = wdeg[key];
                dtot[j] += cnt;
                const ushort* p = idx + s;
                for (int i = 0; i < cnt; i += 4) {
                    ushort4 U = *(const ushort4*)(p + i);   // 4-padded: in-bounds
                    int v1 = (i + 1 < cnt), v2 = (i + 2 < cnt), v3 = (i + 3 < cnt);
                    int s0 = (int)U.x;
                    int s1 = v1 ? (int)U.y : 0;
                    int s2 = v2 ? (int)U.z : 0;
                    int s3 = v3 ? (int)U.w : 0;
                    uint w0 = rowb[(size_t)s0 * 96];
                    uint w1 = rowb[(size_t)s1 * 96];
                    uint w2 = rowb[(size_t)s2 * 96];
                    uint w3 = rowb[(size_t)s3 * 96];
                    if (!v1) w1 = 0; if (!v2) w2 = 0; if (!v3) w3 = 0;
                    a0[j] += (__uint_as_float(w0 << 16) + __uint_as_float(w1 << 16))
                           + (__uint_as_float(w2 << 16) + __uint_as_float(w3 << 16));
                    a1[j] += (__uint_as_float(w0 & 0xFFFF0000u) + __uint_as_float(w1 & 0xFFFF0000u))
                           + (__uint_as_float(w2 & 0xFFFF0000u) + __uint_as_float(w3 & 0xFFFF0000u));
                }
            }
        }
        __syncthreads();   // keep the block's 4 waves in phase
    }

    uint* hb32 = (uint*)hb;
#pragma unroll
    for (int j = 0; j < NPERT; ++j) {
        int n = nn[j];
        if (n < 0) continue;
        float sc = 1.0f / (float)max(dtot[j], 1);
        float A0 = a0[j] * sc, A1 = a1[j] * sc;
        uint bw = (half == 0) ? ((const uint*)proj)[(size_t)n * 96 + 64 + sl] : 0u;
        float b0 = __uint_as_float(bw << 16);
        float b1 = __uint_as_float(bw & 0xFFFF0000u);
        float ss = A0 * A0 + A1 * A1 + b0 * b0 + b1 * b1;
#pragma unroll
        for (int off = 32; off; off >>= 1) ss += __shfl_xor(ss, off);
        float r = 1.0f / fmaxf(sqrtf(ss), 1e-12f);
        A0 *= r; A1 *= r; b0 *= r; b1 *= r;
        A0 = A0 >= 0.f ? A0 : 0.1f * A0;
        A1 = A1 >= 0.f ? A1 : 0.1f * A1;
        hb32[(size_t)n * 96 + half * 32 + sl] = (uint)f2b(A0) | ((uint)f2b(A1) << 16);
        if (half == 0) {
            b0 = b0 >= 0.f ? b0 : 0.1f * b0;
            b1 = b1 >= 0.f ? b1 : 0.1f * b1;
            hb32[(size_t)n * 96 + 64 + sl] = (uint)f2b(b0) | ((uint)f2b(b1) << 16);
        }
    }
}

// ---------------- decoder ----------------
__global__ __launch_bounds__(128) void m1_kernel(const float* __restrict__ P1,
                                                 const float* __restrict__ P2,
                                                 float* __restrict__ tmpM) {
    int i = blockIdx.x, c = threadIdx.x;
    float s = 0.f;
    for (int k = 0; k < 128; ++k) s += P1[i * 128 + k] * P2[k * 128 + c];
    tmpM[i * 128 + c] = s;
}

__global__ __launch_bounds__(192) void m2_kernel(const float* __restrict__ tmpM,
                                                 const float* __restrict__ P1,
                                                 float* __restrict__ M) {
    __shared__ float trow[128];
    int i = blockIdx.x, j = threadIdx.x;
    if (j < 128) trow[j] = tmpM[i * 128 + j];
    __syncthreads();
    float s = 0.f;
    for (int k = 0; k < 128; ++k) s += trow[k] * P1[j * 128 + k];
    M[i * 192 + j] = s;
}

__global__ __launch_bounds__(192) void decode_kernel(const ushort* __restrict__ hb,
                                                     const int* __restrict__ di,
                                                     const float* __restrict__ M,
                                                     float* __restrict__ out) {
    __shared__ alignas(16) float bvs[8][192];
    __shared__ float red[3][8];
    int pb = blockIdx.x * 8;
    int i = threadIdx.x;
#pragma unroll
    for (int p = 0; p < 8; ++p) {
        int nb = di[(pb + p) * 2 + 1] - 1;
        bvs[p][i] = b2f(hb[(size_t)nb * 192 + i]);
    }
    __syncthreads();
    float t[8] = {};
    const float4* M4 = (const float4*)(M + (size_t)i * 192);
    for (int j4 = 0; j4 < 48; ++j4) {
        float4 m = M4[j4];
#pragma unroll
        for (int p = 0; p < 8; ++p) {
            float4 b = *(const float4*)&bvs[p][j4 * 4];
            t[p] += m.x * b.x + m.y * b.y + m.z * b.z + m.w * b.w;
        }
    }
    int wid = i >> 6, lane = i & 63;
#pragma unroll
    for (int p = 0; p < 8; ++p) {
        int na = di[(pb + p) * 2] - 1;
        float v = b2f(hb[(size_t)na * 192 + i]) * t[p];
#pragma unroll
        for (int off = 32; off; off >>= 1) v += __shfl_xor(v, off);
        if (lane == 0) red[wid][p] = v;
    }
    __syncthreads();
    if (i < 8) out[pb + i] = red[0][i] + red[1][i] + red[2][i];
}

extern "C" void kernel_launch(void* const* d_in, const int* in_sizes, int n_in,
                              void* d_out, int out_size, void* d_ws, size_t ws_size,
                              hipStream_t stream) {
    const float* x     = (const float*)d_in[0];
    const int*   ei    = (const int*)d_in[1];
    const int*   di    = (const int*)d_in[2];
    const float* gamma = (const float*)d_in[3];
    const float* beta  = (const float*)d_in[4];
    const float* Wu[3] = {(const float*)d_in[5], (const float*)d_in[8],  (const float*)d_in[11]};
    const float* Wd[3] = {(const float*)d_in[6], (const float*)d_in[9],  (const float*)d_in[12]};
    const float* Wb[3] = {(const float*)d_in[7], (const float*)d_in[10], (const float*)d_in[13]};
    const float* P1    = (const float*)d_in[14];
    const float* P2    = (const float*)d_in[15];
    float* out = (float*)d_out;
    float* ws  = (float*)d_ws;

    float* bn    = ws + OFF_BN;
    int* ccur  = (int*)(ws + OFF_CCUR);
    float* tmpM  = ws + OFF_TMPM;
    float* M     = ws + OFF_M;
    int* woffu = (int*)(ws + OFF_WOFFU);
    int* woffd = (int*)(ws + OFF_WOFFD);
    int* wdegu = (int*)(ws + OFF_WDEGU);
    int* wdegd = (int*)(ws + OFF_WDEGD);
    int* phistu = (int*)(ws + OFF_PHISTU);
    int* phistd = (int*)(ws + OFF_PHISTD);
    ushort* idxu = (ushort*)(ws + OFF_IDXU);
    ushort* idxd = (ushort*)(ws + OFF_IDXD);
    uint* chk  = (uint*)(ws + OFF_CHK);
    ushort* wb16 = (ushort*)(ws + OFF_WB16);
    ushort* hb   = (ushort*)(ws + OFF_HB);
    ushort* proj = (ushort*)(ws + OFF_PROJ);
    ushort* wbl[3] = {wb16, wb16 + 12288, wb16 + 49152};

    hipMemsetAsync(ws, 0, 336 * sizeof(float), stream);          // bn sums + ccur

    bn_stats_kernel<<<200, 256, 0, stream>>>(x, bn, PN);
    bn_finalize_kernel<<<1, 64, 0, stream>>>(gamma, beta, bn, PN);

    bin_kernel<<<512, 256, 0, stream>>>(ei, ccur, chk, PE);
    hist_kernel<<<64 * NSL2, 256, 0, stream>>>(chk, ccur, phistu, phistd);
    scan_kernel<<<2, 1024, 0, stream>>>(phistu, phistd, woffu, woffd, wdegu, wdegd, (int)L4N);
    scatter_kernel<<<64 * NSL2, 256, 0, stream>>>(chk, ccur, phistu, phistd,
                                                  woffu, woffd, idxu, idxd);

    wconv_kernel<64><<<(192 * 64 + 255) / 256, 256, 0, stream>>>(Wu[0], Wd[0], Wb[0], wbl[0]);
    wconv_kernel<192><<<(192 * 192 + 255) / 256, 256, 0, stream>>>(Wu[1], Wd[1], Wb[1], wbl[1]);
    wconv_kernel<192><<<(192 * 192 + 255) / 256, 256, 0, stream>>>(Wu[2], Wd[2], Wb[2], wbl[2]);

    const int ngb = (PN + 127) / 128;
    gemm_kernel<64, true><<<ngb, 256, 0, stream>>>(hb, x, bn, wbl[0], proj, PN);
    gather_kernel<NPER, false><<<GBLK, 256, 0, stream>>>(proj, woffu, wdegu, woffd, wdegd,
                                                         idxu, idxd, di, hb, PN);
    gemm_kernel<192, false><<<ngb, 256, 0, stream>>>(hb, x, bn, wbl[1], proj, PN);
    gather_kernel<NPER, false><<<GBLK, 256, 0, stream>>>(proj, woffu, wdegu, woffd, wdegd,
                                                         idxu, idxd, di, hb, PN);
    gemm_kernel<192, false><<<ngb, 256, 0, stream>>>(hb, x, bn, wbl[2], proj, PN);
    gather_kernel<NPER3, true><<<GBLK3, 256, 0, stream>>>(proj, woffu, wdegu, woffd, wdegd,
                                                          idxu, idxd, di, hb, PN);

    m1_kernel<<<192, 128, 0, stream>>>(P1, P2, tmpM);
    m2_kernel<<<192, 192, 0, stream>>>(tmpM, P1, M);
    decode_kernel<<<PB / 8, 192, 0, stream>>>(hb, di, M, out);
}